// Round 2
// baseline (202.561 us; speedup 1.0000x reference)
//
#include <hip/hip_runtime.h>
#include <cstddef>

// Problem constants (match reference)
#define T_STEPS 32
#define B_SZ    512
#define S_SZ    64
#define F_INPUT 128
#define H1      256
#define H2      256
#define H3      128

// ---------------------------------------------------------------------------
// Kernel 1: latency encoding + mean over S.
// Grid: B_SZ blocks of F_INPUT threads. Thread (b,f) owns channel f of batch b.
// Output rates layout: [t*B + b][f]  (row-major M x K for the first GEMM).
// ---------------------------------------------------------------------------
__global__ void encode_kernel(const float* __restrict__ x,
                              float* __restrict__ rates) {
    const int f = threadIdx.x;   // 0..127
    const int b = blockIdx.x;    // 0..511
    const float* xp = x + (size_t)b * S_SZ * F_INPUT + f;

    float v[S_SZ];
#pragma unroll
    for (int s = 0; s < S_SZ; ++s) {
        float val = xp[(size_t)s * F_INPUT];
        v[s] = (val < 0.75f) ? 0.0f : val;   // gate at ENC_THR
    }
    float mn = v[0], mx = v[0];
#pragma unroll
    for (int s = 1; s < S_SZ; ++s) {
        mn = fminf(mn, v[s]);
        mx = fmaxf(mx, v[s]);
    }

    // Per-thread private histogram column in LDS (no cross-thread sharing;
    // bank = f % 32 so consecutive lanes hit distinct banks).
    __shared__ float hist[T_STEPS * F_INPUT];   // 16 KB
#pragma unroll
    for (int t = 0; t < T_STEPS; ++t) hist[t * F_INPUT + f] = 0.0f;

    const float denom = mx - mn + 1e-8f;
    for (int s = 0; s < S_SZ; ++s) {
        float xn = (v[s] - mn) / denom;
        float d  = fmaxf(xn, 0.0100001f);              // clip(xn, LAT_THR+EPS)
        float tt = logf(d / (d - 0.01f));              // log latency code
        tt = tt * 31.0f;                               // * (num_steps-1)
        tt = tt / 11.512935464920229f;                 // / float32(log((thr+eps)/eps))
        float tr = rintf(tt);                          // round half-to-even == jnp.round
        tr = fminf(fmaxf(tr, 0.0f), 31.0f);
        hist[(int)tr * F_INPUT + f] += 1.0f;
    }

    const size_t bf = (size_t)b * F_INPUT + f;
#pragma unroll
    for (int t = 0; t < T_STEPS; ++t) {
        // mean over S: count / 64 (exact)
        rates[(size_t)t * (B_SZ * F_INPUT) + bf] = hist[t * F_INPUT + f] * 0.015625f;
    }
}

// ---------------------------------------------------------------------------
// Kernel 2: fp32 GEMM with bias:  C[m][n] = sum_k A[m][k] * W[n][k] + bias[n]
// A: M x K row-major, W: N x K row-major (einsum 'mk,nk->mn').
// 64x64 tile, BK=32, 256 threads, 4x4 micro-tile per thread.
// M % 64 == 0, N % 64 == 0, K % 32 == 0 guaranteed by problem sizes.
// ---------------------------------------------------------------------------
#define BM 64
#define BN 64
#define BK 32

__global__ __launch_bounds__(256)
void gemm_bias_kernel(const float* __restrict__ A,
                      const float* __restrict__ W,
                      const float* __restrict__ bias,
                      float* __restrict__ C,
                      int M, int N, int K) {
    __shared__ float As[BK][BM];   // 8 KB
    __shared__ float Bs[BK][BN];   // 8 KB

    const int tid = threadIdx.x;
    const int m0 = blockIdx.x * BM;
    const int n0 = blockIdx.y * BN;
    const int tx = tid & 15;        // n micro-tile index
    const int ty = tid >> 4;        // m micro-tile index

    float acc[4][4] = {};

    for (int k0 = 0; k0 < K; k0 += BK) {
        // Stage A tile (BM x BK = 512 float4 loads, 2 per thread), transposed
#pragma unroll
        for (int r = 0; r < 2; ++r) {
            int j  = r * 256 + tid;
            int m  = j >> 3;
            int c4 = (j & 7) * 4;
            float4 val = *(const float4*)(A + (size_t)(m0 + m) * K + k0 + c4);
            As[c4 + 0][m] = val.x;
            As[c4 + 1][m] = val.y;
            As[c4 + 2][m] = val.z;
            As[c4 + 3][m] = val.w;
        }
        // Stage W tile (BN x BK), transposed into Bs[k][n]
#pragma unroll
        for (int r = 0; r < 2; ++r) {
            int j  = r * 256 + tid;
            int n  = j >> 3;
            int c4 = (j & 7) * 4;
            float4 val = *(const float4*)(W + (size_t)(n0 + n) * K + k0 + c4);
            Bs[c4 + 0][n] = val.x;
            Bs[c4 + 1][n] = val.y;
            Bs[c4 + 2][n] = val.z;
            Bs[c4 + 3][n] = val.w;
        }
        __syncthreads();

#pragma unroll
        for (int k = 0; k < BK; ++k) {
            float a[4], bv[4];
#pragma unroll
            for (int i = 0; i < 4; ++i) a[i]  = As[k][ty * 4 + i];
#pragma unroll
            for (int j = 0; j < 4; ++j) bv[j] = Bs[k][tx * 4 + j];
#pragma unroll
            for (int i = 0; i < 4; ++i)
#pragma unroll
                for (int j = 0; j < 4; ++j)
                    acc[i][j] += a[i] * bv[j];
        }
        __syncthreads();
    }

#pragma unroll
    for (int j = 0; j < 4; ++j) {
        float bj = bias[n0 + tx * 4 + j];
#pragma unroll
        for (int i = 0; i < 4; ++i) {
            C[(size_t)(m0 + ty * 4 + i) * N + n0 + tx * 4 + j] = acc[i][j] + bj;
        }
    }
}

// ---------------------------------------------------------------------------
// Kernel 3: LIF scan (reset-by-subtraction), sequential over T per (b,h).
// cur/spk layout: [t*B + b][h]; thread id = b*H + h, so element = t*BH + id.
// fp contract OFF: reference computes (beta*mem + c) - reset with separate
// mul/add — fma would change rounding at the spike threshold.
// ---------------------------------------------------------------------------
__global__ void lif_scan_kernel(const float* __restrict__ cur,
                                float* __restrict__ spk,
                                int BH) {
#pragma clang fp contract(off)
    int id = blockIdx.x * blockDim.x + threadIdx.x;
    if (id >= BH) return;
    float mem = 0.0f;
#pragma unroll
    for (int t = 0; t < T_STEPS; ++t) {
        float c = cur[(size_t)t * BH + id];
        float reset = (mem - 1.0f > 0.0f) ? 1.0f : 0.0f;
        float p = 0.9f * mem;
        p = p + c;
        mem = p - reset;   // reset * thr, thr = 1.0
        spk[(size_t)t * BH + id] = (mem - 1.0f > 0.0f) ? 1.0f : 0.0f;
    }
}

// ---------------------------------------------------------------------------
extern "C" void kernel_launch(void* const* d_in, const int* in_sizes, int n_in,
                              void* d_out, int out_size, void* d_ws, size_t ws_size,
                              hipStream_t stream) {
    const float* x  = (const float*)d_in[0];
    const float* W1 = (const float*)d_in[1];
    const float* b1 = (const float*)d_in[2];
    const float* W2 = (const float*)d_in[3];
    const float* b2 = (const float*)d_in[4];
    const float* W3 = (const float*)d_in[5];
    const float* b3 = (const float*)d_in[6];
    float* out = (float*)d_out;

    char* ws = (char*)d_ws;
    float* buf0 = (float*)ws;                               // 16 MB
    float* buf1 = (float*)(ws + (size_t)16 * 1024 * 1024);  // 16 MB

    const int M = T_STEPS * B_SZ;          // 16384

    // 1. encode: x -> rates (M x 128) in buf0
    encode_kernel<<<B_SZ, F_INPUT, 0, stream>>>(x, buf0);

    // 2. layer 1: cur1 = rates @ W1^T + b1  (M x 256) in buf1
    gemm_bias_kernel<<<dim3(M / BM, H1 / BN), 256, 0, stream>>>(
        buf0, W1, b1, buf1, M, H1, F_INPUT);
    // 3. LIF scan 1: spk1 in buf0
    lif_scan_kernel<<<(B_SZ * H1) / 256, 256, 0, stream>>>(buf1, buf0, B_SZ * H1);

    // 4. layer 2
    gemm_bias_kernel<<<dim3(M / BM, H2 / BN), 256, 0, stream>>>(
        buf0, W2, b2, buf1, M, H2, H1);
    lif_scan_kernel<<<(B_SZ * H2) / 256, 256, 0, stream>>>(buf1, buf0, B_SZ * H2);

    // 5. layer 3 -> d_out
    gemm_bias_kernel<<<dim3(M / BM, H3 / BN), 256, 0, stream>>>(
        buf0, W3, b3, buf1, M, H3, H2);
    lif_scan_kernel<<<(B_SZ * H3) / 256, 256, 0, stream>>>(buf1, out, B_SZ * H3);
}

// Round 3
// 190.190 us; speedup vs baseline: 1.0650x; 1.0650x over previous
//
#include <hip/hip_runtime.h>
#include <cstddef>

// Problem constants (match reference)
#define T_STEPS 32
#define B_SZ    512
#define S_SZ    64
#define F_INPUT 128
#define H1      256
#define H2      256
#define H3      128

typedef _Float16 half_t;
typedef __attribute__((ext_vector_type(8))) _Float16 half8;
typedef __attribute__((ext_vector_type(4))) float   float4v;

// ---------------------------------------------------------------------------
// Kernel 1: latency encoding + mean over S. Rewritten vs R2: NO per-thread
// v[64] array (it spilled to scratch: VGPR_Count=40, 64us at 0.17% VALUBusy).
// Two streaming passes over x; second pass hits L1/L2. Block = 256 threads =
// 2 batches. Emits rates directly as f16 (exact: k/64, k<=64 fits 8 bits).
// ---------------------------------------------------------------------------
__global__ __launch_bounds__(256)
void encode_kernel(const float* __restrict__ x, half_t* __restrict__ rates) {
    const int f = threadIdx.x & 127;
    const int half_id = threadIdx.x >> 7;            // which batch of the pair
    const int b = blockIdx.x * 2 + half_id;
    const float* xp = x + (size_t)b * (S_SZ * F_INPUT) + f;

    // pass 1: min/max of gated values
    float mn = 1e30f, mx = -1e30f;
    for (int s = 0; s < S_SZ; ++s) {
        float val = xp[(size_t)s * F_INPUT];
        float g = (val < 0.75f) ? 0.0f : val;        // gate at ENC_THR
        mn = fminf(mn, g);
        mx = fmaxf(mx, g);
    }

    // per-thread private histogram column in LDS (lanes f -> bank f%32, 2-way = free)
    __shared__ float hist[2][T_STEPS][F_INPUT];      // 32 KB
    float* hcol = &hist[half_id][0][f];
#pragma unroll
    for (int t = 0; t < T_STEPS; ++t) hcol[t * F_INPUT] = 0.0f;

    const float denom = mx - mn + 1e-8f;
    // pass 2: recompute gated value (L1/L2-hot reload), bin, histogram
    for (int s = 0; s < S_SZ; ++s) {
        float val = xp[(size_t)s * F_INPUT];
        float g = (val < 0.75f) ? 0.0f : val;
        float xn = (g - mn) / denom;
        float d  = fmaxf(xn, 0.0100001f);            // clip(xn, LAT_THR+EPS)
        float tt = logf(d / (d - 0.01f));            // log latency code
        tt = tt * 31.0f;                             // * (num_steps-1)
        tt = tt / 11.512935464920229f;               // / float32(log((thr+eps)/eps))
        float tr = rintf(tt);                        // half-to-even == jnp.round
        tr = fminf(fmaxf(tr, 0.0f), 31.0f);
        hcol[(int)tr * F_INPUT] += 1.0f;
    }

    const size_t col = (size_t)b * F_INPUT + f;
#pragma unroll
    for (int t = 0; t < T_STEPS; ++t) {
        // mean over S: count/64, exact in f16 (<= 8 significant bits)
        rates[(size_t)t * (B_SZ * F_INPUT) + col] =
            (half_t)(hcol[t * F_INPUT] * 0.015625f);
    }
}

// ---------------------------------------------------------------------------
// Kernel 2: MFMA GEMM with exact split-f16 weights.
//   C[m][n] = sum_k A[m][k] * W[n][k] + bias[n]
// A: [M][K] f16 (values exact: rates k/64 or spikes 0/1).
// W: [N][K] f32, split on the fly during staging:
//   hi = f16(w) (flushed to 0 if f16-denormal), lo = f16((w - hi) * 2^12).
// K' = 2K passes: lo-pass accumulates first, acc *= 2^-12 at the boundary,
// hi-pass adds on top  =>  C = sum(A*hi) + 2^-12 * sum(A*lo)  (~fp32-exact W).
// Tiles: 128x128 block, 4 waves 2x2, each wave 64x64 = 4x4 mfma 16x16x32 f16.
// LDS rows padded 64->72 halfs: frag-read/store aliasing is 2-way (free, m136).
// ---------------------------------------------------------------------------
#define BM  128
#define BN  128
#define BKH 64    // K'-chunk (halfs) per stage
#define LDA 72    // padded LDS row stride (halfs); 144 B, 16B-aligned rows

__global__ __launch_bounds__(256)
void gemm_split_kernel(const half_t* __restrict__ A,
                       const float*  __restrict__ W,
                       const float*  __restrict__ bias,
                       float* __restrict__ C,
                       int M, int N, int K) {
    __shared__ half_t As[BM * LDA];   // 18432 B
    __shared__ half_t Ws[BN * LDA];   // 18432 B

    const int tid  = threadIdx.x;
    const int m0   = blockIdx.x * BM;
    const int n0   = blockIdx.y * BN;
    const int wave = tid >> 6;
    const int lane = tid & 63;
    const int wm   = (wave >> 1) * 64;   // wave row offset in tile
    const int wn   = (wave & 1) * 64;    // wave col offset in tile
    const int quad = lane >> 4;
    const int lr   = lane & 15;

    float4v acc[4][4];
#pragma unroll
    for (int i = 0; i < 4; ++i)
#pragma unroll
        for (int j = 0; j < 4; ++j)
            acc[i][j] = (float4v){0.0f, 0.0f, 0.0f, 0.0f};

    // staging decomposition: 1024 16B-chunks per tile, 4 per thread
    const int srow  = tid >> 3;          // 0..31, +32*i
    const int skoff = (tid & 7) * 8;     // half offset within row

    const int loStages = K / BKH;        // stages in the lo pass
    const int nStages  = 2 * loStages;   // total (lo then hi)

    for (int ks = 0; ks < nStages; ++ks) {
        const bool loPass = (ks < loStages);
        const int  k0 = (loPass ? ks : ks - loStages) * BKH;

        // ---- stage A tile (f16, direct) ----
#pragma unroll
        for (int i = 0; i < 4; ++i) {
            int r = srow + i * 32;
            uint4 v = *(const uint4*)(A + (size_t)(m0 + r) * K + k0 + skoff);
            *(uint4*)(&As[r * LDA + skoff]) = v;
        }
        // ---- stage W tile (f32 -> split f16) ----
#pragma unroll
        for (int i = 0; i < 4; ++i) {
            int r = srow + i * 32;
            const float* wp = W + (size_t)(n0 + r) * K + k0 + skoff;
            float4 w0 = *(const float4*)(wp);
            float4 w1 = *(const float4*)(wp + 4);
            float wf[8] = {w0.x, w0.y, w0.z, w0.w, w1.x, w1.y, w1.z, w1.w};
            half_t h[8];
#pragma unroll
            for (int j = 0; j < 8; ++j) {
                float w = wf[j];
                half_t hi = (half_t)w;
                float hif = (float)hi;
                // avoid MFMA f16-denormal ambiguity: flush hi, let lo carry it
                if (fabsf(hif) < 6.103515625e-05f) { hi = (half_t)0.0f; hif = 0.0f; }
                if (loPass) {
                    h[j] = (half_t)((w - hif) * 4096.0f);  // residual, scaled to normal range
                } else {
                    h[j] = hi;
                }
            }
            *(uint4*)(&Ws[r * LDA + skoff]) = *(uint4*)h;
        }
        __syncthreads();

        // lo->hi boundary: fold 2^-12 into the lo partial sums (once)
        if (ks == loStages) {
#pragma unroll
            for (int i = 0; i < 4; ++i)
#pragma unroll
                for (int j = 0; j < 4; ++j)
                    acc[i][j] *= 2.44140625e-04f;   // 2^-12
        }

        // ---- compute: 2 k-steps of 32, 16 mfma each ----
#pragma unroll
        for (int kk = 0; kk < 2; ++kk) {
            half8 af[4], bf[4];
#pragma unroll
            for (int mt = 0; mt < 4; ++mt)
                af[mt] = *(const half8*)(&As[(wm + mt * 16 + lr) * LDA + kk * 32 + quad * 8]);
#pragma unroll
            for (int nt = 0; nt < 4; ++nt)
                bf[nt] = *(const half8*)(&Ws[(wn + nt * 16 + lr) * LDA + kk * 32 + quad * 8]);
#pragma unroll
            for (int mt = 0; mt < 4; ++mt)
#pragma unroll
                for (int nt = 0; nt < 4; ++nt)
                    acc[mt][nt] = __builtin_amdgcn_mfma_f32_16x16x32_f16(
                        af[mt], bf[nt], acc[mt][nt], 0, 0, 0);
        }
        __syncthreads();
    }

    // epilogue: C/D layout col=lane&15, row=quad*4+reg (m89-verified)
#pragma unroll
    for (int nt = 0; nt < 4; ++nt) {
        int n = n0 + wn + nt * 16 + lr;
        float bj = bias[n];
#pragma unroll
        for (int mt = 0; mt < 4; ++mt) {
            int mbase = m0 + wm + mt * 16 + quad * 4;
#pragma unroll
            for (int r = 0; r < 4; ++r)
                C[(size_t)(mbase + r) * N + n] = acc[mt][nt][r] + bj;
        }
    }
}

// ---------------------------------------------------------------------------
// Kernel 3: LIF scan (reset-by-subtraction), sequential over T per (b,h).
// fp contract OFF: reference does separate mul/add/sub — fma would change
// rounding at the spike threshold. f16 variant feeds the next GEMM (0/1 exact).
// ---------------------------------------------------------------------------
__global__ void lif_scan_f16(const float* __restrict__ cur,
                             half_t* __restrict__ spk, int BH) {
#pragma clang fp contract(off)
    int id = blockIdx.x * blockDim.x + threadIdx.x;
    float mem = 0.0f;
#pragma unroll
    for (int t = 0; t < T_STEPS; ++t) {
        float c = cur[(size_t)t * BH + id];
        float reset = (mem - 1.0f > 0.0f) ? 1.0f : 0.0f;
        float p = 0.9f * mem;
        p = p + c;
        mem = p - reset;
        spk[(size_t)t * BH + id] = (half_t)((mem - 1.0f > 0.0f) ? 1.0f : 0.0f);
    }
}

__global__ void lif_scan_f32(const float* __restrict__ cur,
                             float* __restrict__ spk, int BH) {
#pragma clang fp contract(off)
    int id = blockIdx.x * blockDim.x + threadIdx.x;
    float mem = 0.0f;
#pragma unroll
    for (int t = 0; t < T_STEPS; ++t) {
        float c = cur[(size_t)t * BH + id];
        float reset = (mem - 1.0f > 0.0f) ? 1.0f : 0.0f;
        float p = 0.9f * mem;
        p = p + c;
        mem = p - reset;
        spk[(size_t)t * BH + id] = (mem - 1.0f > 0.0f) ? 1.0f : 0.0f;
    }
}

// ---------------------------------------------------------------------------
extern "C" void kernel_launch(void* const* d_in, const int* in_sizes, int n_in,
                              void* d_out, int out_size, void* d_ws, size_t ws_size,
                              hipStream_t stream) {
    const float* x  = (const float*)d_in[0];
    const float* W1 = (const float*)d_in[1];
    const float* b1 = (const float*)d_in[2];
    const float* W2 = (const float*)d_in[3];
    const float* b2 = (const float*)d_in[4];
    const float* W3 = (const float*)d_in[5];
    const float* b3 = (const float*)d_in[6];
    float* out = (float*)d_out;

    char* ws = (char*)d_ws;
    float*  cur = (float*)ws;                                  // 16 MB
    half_t* A0  = (half_t*)(ws + (size_t)16 * 1024 * 1024);    //  8 MB
    half_t* A1  = (half_t*)(ws + (size_t)24 * 1024 * 1024);    //  8 MB
    // total 32 MB (same footprint R0 proved available)

    const int M = T_STEPS * B_SZ;   // 16384

    // 1. encode: x -> rates f16 (M x 128) in A0
    encode_kernel<<<B_SZ / 2, 256, 0, stream>>>(x, A0);

    // 2. layer 1: cur = A0 @ W1^T + b1   (M x 256)
    gemm_split_kernel<<<dim3(M / BM, H1 / BN), 256, 0, stream>>>(
        A0, W1, b1, cur, M, H1, F_INPUT);
    lif_scan_f16<<<(B_SZ * H1) / 256, 256, 0, stream>>>(cur, A1, B_SZ * H1);

    // 3. layer 2
    gemm_split_kernel<<<dim3(M / BM, H2 / BN), 256, 0, stream>>>(
        A1, W2, b2, cur, M, H2, H1);
    lif_scan_f16<<<(B_SZ * H2) / 256, 256, 0, stream>>>(cur, A0, B_SZ * H2);

    // 4. layer 3 -> d_out (f32)
    gemm_split_kernel<<<dim3(M / BM, H3 / BN), 256, 0, stream>>>(
        A0, W3, b3, cur, M, H3, H2);
    lif_scan_f32<<<(B_SZ * H3) / 256, 256, 0, stream>>>(cur, out, B_SZ * H3);
}

// Round 4
// 138.540 us; speedup vs baseline: 1.4621x; 1.3728x over previous
//
#include <hip/hip_runtime.h>
#include <cstddef>

// Problem constants (match reference)
#define T_STEPS 32
#define B_SZ    512
#define S_SZ    64
#define F_INPUT 128
#define H1      256
#define H2      256
#define H3      128

typedef _Float16 half_t;
typedef __attribute__((ext_vector_type(8))) _Float16 half8;
typedef __attribute__((ext_vector_type(4))) float   float4v;

// ---------------------------------------------------------------------------
// Kernel 0: pre-split all three weight matrices into interleaved hi/lo f16.
//   hi = f16(w) (flushed if f16-denormal), lo = f16((w - hi) * 2^12)
// Layout: whl[n][2K], where k-chunk c occupies [64c,64c+32) = hi, +32 = lo.
// One dispatch covers all 131072 weights (~1 MB traffic, ~2 us).
// ---------------------------------------------------------------------------
__device__ inline void split_store(float w, half_t* out, int n, int K2, int k) {
    half_t hi = (half_t)w;
    float hif = (float)hi;
    if (fabsf(hif) < 6.103515625e-05f) { hi = (half_t)0.0f; hif = 0.0f; }
    half_t lo = (half_t)((w - hif) * 4096.0f);
    int chunk = k >> 5, kin = k & 31;
    out[(size_t)n * K2 + chunk * 64 + kin]      = hi;
    out[(size_t)n * K2 + chunk * 64 + 32 + kin] = lo;
}

__global__ __launch_bounds__(256)
void prep_w_kernel(const float* __restrict__ W1, const float* __restrict__ W2,
                   const float* __restrict__ W3,
                   half_t* __restrict__ whl1, half_t* __restrict__ whl2,
                   half_t* __restrict__ whl3) {
    int e = blockIdx.x * blockDim.x + threadIdx.x;   // 0..131071
    if (e < H1 * F_INPUT) {                          // layer 1: 256 x 128
        split_store(W1[e], whl1, e / F_INPUT, 2 * F_INPUT, e % F_INPUT);
    } else if (e < H1 * F_INPUT + H2 * H1) {         // layer 2: 256 x 256
        int i = e - H1 * F_INPUT;
        split_store(W2[i], whl2, i / H1, 2 * H1, i % H1);
    } else {                                         // layer 3: 128 x 256
        int i = e - H1 * F_INPUT - H2 * H1;
        split_store(W3[i], whl3, i / H2, 2 * H2, i % H2);
    }
}

// ---------------------------------------------------------------------------
// Kernel 1: latency encoding + mean over S (R3 version — no per-thread spill).
// ---------------------------------------------------------------------------
__global__ __launch_bounds__(256)
void encode_kernel(const float* __restrict__ x, half_t* __restrict__ rates) {
    const int f = threadIdx.x & 127;
    const int half_id = threadIdx.x >> 7;
    const int b = blockIdx.x * 2 + half_id;
    const float* xp = x + (size_t)b * (S_SZ * F_INPUT) + f;

    float mn = 1e30f, mx = -1e30f;
    for (int s = 0; s < S_SZ; ++s) {
        float val = xp[(size_t)s * F_INPUT];
        float g = (val < 0.75f) ? 0.0f : val;        // gate at ENC_THR
        mn = fminf(mn, g);
        mx = fmaxf(mx, g);
    }

    __shared__ float hist[2][T_STEPS][F_INPUT];      // 32 KB
    float* hcol = &hist[half_id][0][f];
#pragma unroll
    for (int t = 0; t < T_STEPS; ++t) hcol[t * F_INPUT] = 0.0f;

    const float denom = mx - mn + 1e-8f;
    for (int s = 0; s < S_SZ; ++s) {
        float val = xp[(size_t)s * F_INPUT];
        float g = (val < 0.75f) ? 0.0f : val;
        float xn = (g - mn) / denom;
        float d  = fmaxf(xn, 0.0100001f);            // clip(xn, LAT_THR+EPS)
        float tt = logf(d / (d - 0.01f));            // log latency code
        tt = tt * 31.0f;
        tt = tt / 11.512935464920229f;               // float32(log((thr+eps)/eps))
        float tr = rintf(tt);                        // half-to-even == jnp.round
        tr = fminf(fmaxf(tr, 0.0f), 31.0f);
        hcol[(int)tr * F_INPUT] += 1.0f;
    }

    const size_t col = (size_t)b * F_INPUT + f;
#pragma unroll
    for (int t = 0; t < T_STEPS; ++t)
        rates[(size_t)t * (B_SZ * F_INPUT) + col] =
            (half_t)(hcol[t * F_INPUT] * 0.015625f);
}

// ---------------------------------------------------------------------------
// Kernel 2: MFMA GEMM, pre-split f16 weights, single K-pass, dual accumulator.
//   C[m][n] = sum_k A[m][k]*hi[n][k]  +  2^-12 * sum_k A[m][k]*lo[n][k]  + b[n]
// Block tile 128x64 (M x N), 4 waves 2x2, wave tile 64x32. BK=64 halfs/stage.
// Grid: gemm1/2 = 512 blocks, gemm3 = 256 (vs R3's 256/128: 2-4x occupancy —
// R3 ran 1 wave/SIMD with zero latency-hiding headroom).
// A frag is reused for hi and lo MFMA: 32 mfma : 16 ds_read_b128 per stage.
// ---------------------------------------------------------------------------
#define BM   128
#define BN   64
#define BKH  64     // original-K halfs per stage
#define LDA  72     // As row stride (halfs): row shift = 4 banks, 2-way free
#define LDW  136    // Ws row stride (halfs): 2*BKH + 8

__global__ __launch_bounds__(256)
void gemm_split_kernel(const half_t* __restrict__ A,
                       const half_t* __restrict__ Whl,
                       const float*  __restrict__ bias,
                       float* __restrict__ C,
                       int M, int N, int K) {
    __shared__ half_t As[BM * LDA];   // 18432 B
    __shared__ half_t Ws[BN * LDW];   // 17408 B

    const int tid  = threadIdx.x;
    const int m0   = blockIdx.x * BM;
    const int n0   = blockIdx.y * BN;
    const int wave = tid >> 6;
    const int lane = tid & 63;
    const int wm   = (wave >> 1) * 64;   // wave row offset
    const int wn   = (wave & 1) * 32;    // wave col offset
    const int quad = lane >> 4;
    const int lr   = lane & 15;
    const int K2   = 2 * K;

    float4v acc_h[4][2], acc_l[4][2];
#pragma unroll
    for (int i = 0; i < 4; ++i)
#pragma unroll
        for (int j = 0; j < 2; ++j) {
            acc_h[i][j] = (float4v){0.0f, 0.0f, 0.0f, 0.0f};
            acc_l[i][j] = (float4v){0.0f, 0.0f, 0.0f, 0.0f};
        }

    // A staging: 128 rows x 64 halfs = 1024 x 16B chunks, 4/thread
    const int arow = tid >> 3;           // 0..31 (+32*i)
    const int aoff = (tid & 7) * 8;
    // W staging: 64 rows x 128 halfs = 1024 x 16B chunks, 4/thread
    const int wrow = tid >> 4;           // 0..15 (+16*i)
    const int woff = (tid & 15) * 8;

    for (int k0 = 0; k0 < K; k0 += BKH) {
#pragma unroll
        for (int i = 0; i < 4; ++i) {
            int r = arow + i * 32;
            *(uint4*)(&As[r * LDA + aoff]) =
                *(const uint4*)(A + (size_t)(m0 + r) * K + k0 + aoff);
        }
#pragma unroll
        for (int i = 0; i < 4; ++i) {
            int r = wrow + i * 16;
            *(uint4*)(&Ws[r * LDW + woff]) =
                *(const uint4*)(Whl + (size_t)(n0 + r) * K2 + 2 * k0 + woff);
        }
        __syncthreads();

#pragma unroll
        for (int kk = 0; kk < 2; ++kk) {
            half8 af[4], wh[2], wl[2];
#pragma unroll
            for (int mt = 0; mt < 4; ++mt)
                af[mt] = *(const half8*)(&As[(wm + mt * 16 + lr) * LDA + kk * 32 + quad * 8]);
#pragma unroll
            for (int nt = 0; nt < 2; ++nt) {
                const half_t* wp = &Ws[(wn + nt * 16 + lr) * LDW + kk * 64 + quad * 8];
                wh[nt] = *(const half8*)(wp);
                wl[nt] = *(const half8*)(wp + 32);
            }
#pragma unroll
            for (int mt = 0; mt < 4; ++mt)
#pragma unroll
                for (int nt = 0; nt < 2; ++nt) {
                    acc_h[mt][nt] = __builtin_amdgcn_mfma_f32_16x16x32_f16(
                        af[mt], wh[nt], acc_h[mt][nt], 0, 0, 0);
                    acc_l[mt][nt] = __builtin_amdgcn_mfma_f32_16x16x32_f16(
                        af[mt], wl[nt], acc_l[mt][nt], 0, 0, 0);
                }
        }
        __syncthreads();
    }

    // epilogue: C/D layout col=lane&15, row=quad*4+reg (m89-verified)
#pragma unroll
    for (int nt = 0; nt < 2; ++nt) {
        int n = n0 + wn + nt * 16 + lr;
        float bj = bias[n];
#pragma unroll
        for (int mt = 0; mt < 4; ++mt) {
            int mbase = m0 + wm + mt * 16 + quad * 4;
#pragma unroll
            for (int r = 0; r < 4; ++r) {
                float v = acc_h[mt][nt][r] + 2.44140625e-04f * acc_l[mt][nt][r];
                C[(size_t)(mbase + r) * N + n] = v + bj;
            }
        }
    }
}

// ---------------------------------------------------------------------------
// Kernel 3: LIF scan (reset-by-subtraction). fp contract OFF: reference does
// separate mul/add/sub — fma would change rounding at the spike threshold.
// ---------------------------------------------------------------------------
__global__ void lif_scan_f16(const float* __restrict__ cur,
                             half_t* __restrict__ spk, int BH) {
#pragma clang fp contract(off)
    int id = blockIdx.x * blockDim.x + threadIdx.x;
    float mem = 0.0f;
#pragma unroll
    for (int t = 0; t < T_STEPS; ++t) {
        float c = cur[(size_t)t * BH + id];
        float reset = (mem - 1.0f > 0.0f) ? 1.0f : 0.0f;
        float p = 0.9f * mem;
        p = p + c;
        mem = p - reset;
        spk[(size_t)t * BH + id] = (half_t)((mem - 1.0f > 0.0f) ? 1.0f : 0.0f);
    }
}

__global__ void lif_scan_f32(const float* __restrict__ cur,
                             float* __restrict__ spk, int BH) {
#pragma clang fp contract(off)
    int id = blockIdx.x * blockDim.x + threadIdx.x;
    float mem = 0.0f;
#pragma unroll
    for (int t = 0; t < T_STEPS; ++t) {
        float c = cur[(size_t)t * BH + id];
        float reset = (mem - 1.0f > 0.0f) ? 1.0f : 0.0f;
        float p = 0.9f * mem;
        p = p + c;
        mem = p - reset;
        spk[(size_t)t * BH + id] = (mem - 1.0f > 0.0f) ? 1.0f : 0.0f;
    }
}

// ---------------------------------------------------------------------------
extern "C" void kernel_launch(void* const* d_in, const int* in_sizes, int n_in,
                              void* d_out, int out_size, void* d_ws, size_t ws_size,
                              hipStream_t stream) {
    const float* x  = (const float*)d_in[0];
    const float* W1 = (const float*)d_in[1];
    const float* b1 = (const float*)d_in[2];
    const float* W2 = (const float*)d_in[3];
    const float* b2 = (const float*)d_in[4];
    const float* W3 = (const float*)d_in[5];
    const float* b3 = (const float*)d_in[6];
    float* out = (float*)d_out;

    char* ws = (char*)d_ws;
    float*  cur  = (float*)ws;                                   // 16 MB
    half_t* A0   = (half_t*)(ws + (size_t)16 * 1024 * 1024);     //  8 MB
    half_t* A1   = (half_t*)(ws + (size_t)24 * 1024 * 1024);     //  8 MB
    half_t* whl1 = (half_t*)(ws + (size_t)32 * 1024 * 1024);     // 128 KB (256 x 256 h)
    half_t* whl2 = (half_t*)(ws + (size_t)33 * 1024 * 1024);     // 256 KB (256 x 512 h)
    half_t* whl3 = (half_t*)(ws + (size_t)34 * 1024 * 1024);     // 128 KB (128 x 512 h)

    const int M = T_STEPS * B_SZ;   // 16384

    // 0. split weights (all layers, one dispatch)
    prep_w_kernel<<<(H1 * F_INPUT + H2 * H1 + H3 * H2) / 256, 256, 0, stream>>>(
        W1, W2, W3, whl1, whl2, whl3);

    // 1. encode: x -> rates f16 (M x 128) in A0
    encode_kernel<<<B_SZ / 2, 256, 0, stream>>>(x, A0);

    // 2. layer 1: cur = A0 @ W1^T + b1   (M x 256)
    gemm_split_kernel<<<dim3(M / BM, H1 / BN), 256, 0, stream>>>(
        A0, whl1, b1, cur, M, H1, F_INPUT);
    lif_scan_f16<<<(B_SZ * H1) / 256, 256, 0, stream>>>(cur, A1, B_SZ * H1);

    // 3. layer 2
    gemm_split_kernel<<<dim3(M / BM, H2 / BN), 256, 0, stream>>>(
        A1, whl2, b2, cur, M, H2, H1);
    lif_scan_f16<<<(B_SZ * H2) / 256, 256, 0, stream>>>(cur, A0, B_SZ * H2);

    // 4. layer 3 -> d_out (f32)
    gemm_split_kernel<<<dim3(M / BM, H3 / BN), 256, 0, stream>>>(
        A0, whl3, b3, cur, M, H3, H2);
    lif_scan_f32<<<(B_SZ * H3) / 256, 256, 0, stream>>>(cur, out, B_SZ * H3);
}

// Round 5
// 118.456 us; speedup vs baseline: 1.7100x; 1.1695x over previous
//
#include <hip/hip_runtime.h>
#include <cstddef>

// Problem constants (match reference)
#define T_STEPS 32
#define B_SZ    512
#define S_SZ    64
#define F_INPUT 128
#define H1      256
#define H2      256
#define H3      128

typedef _Float16 half_t;
typedef __attribute__((ext_vector_type(8))) _Float16 half8;
typedef __attribute__((ext_vector_type(4))) float   float4v;

// ---------------------------------------------------------------------------
// Kernel 0: pre-split weights into interleaved hi/lo f16 (unchanged from R4).
//   hi = f16(w) (flushed if f16-denormal), lo = f16((w - hi) * 2^12)
// whl[n][2K]: k-chunk c at [64c, 64c+32) = hi, [64c+32, 64c+64) = lo.
// ---------------------------------------------------------------------------
__device__ inline void split_store(float w, half_t* out, int n, int K2, int k) {
    half_t hi = (half_t)w;
    float hif = (float)hi;
    if (fabsf(hif) < 6.103515625e-05f) { hi = (half_t)0.0f; hif = 0.0f; }
    half_t lo = (half_t)((w - hif) * 4096.0f);
    int chunk = k >> 5, kin = k & 31;
    out[(size_t)n * K2 + chunk * 64 + kin]      = hi;
    out[(size_t)n * K2 + chunk * 64 + 32 + kin] = lo;
}

__global__ __launch_bounds__(256)
void prep_w_kernel(const float* __restrict__ W1, const float* __restrict__ W2,
                   const float* __restrict__ W3,
                   half_t* __restrict__ whl1, half_t* __restrict__ whl2,
                   half_t* __restrict__ whl3) {
    int e = blockIdx.x * blockDim.x + threadIdx.x;
    if (e < H1 * F_INPUT) {
        split_store(W1[e], whl1, e / F_INPUT, 2 * F_INPUT, e % F_INPUT);
    } else if (e < H1 * F_INPUT + H2 * H1) {
        int i = e - H1 * F_INPUT;
        split_store(W2[i], whl2, i / H1, 2 * H1, i % H1);
    } else {
        int i = e - H1 * F_INPUT - H2 * H1;
        split_store(W3[i], whl3, i / H2, 2 * H2, i % H2);
    }
}

// ---------------------------------------------------------------------------
// Kernel 1: latency encoding + mean over S.
// CHANGED vs R4: rates layout is now b-major, row m = b*32 + t. A 128-row
// GEMM tile then holds 4 complete batches x 32 timesteps -> LIF fusable.
// ---------------------------------------------------------------------------
__global__ __launch_bounds__(256)
void encode_kernel(const float* __restrict__ x, half_t* __restrict__ rates) {
    const int f = threadIdx.x & 127;
    const int half_id = threadIdx.x >> 7;
    const int b = blockIdx.x * 2 + half_id;
    const float* xp = x + (size_t)b * (S_SZ * F_INPUT) + f;

    float mn = 1e30f, mx = -1e30f;
    for (int s = 0; s < S_SZ; ++s) {
        float val = xp[(size_t)s * F_INPUT];
        float g = (val < 0.75f) ? 0.0f : val;        // gate at ENC_THR
        mn = fminf(mn, g);
        mx = fmaxf(mx, g);
    }

    __shared__ float hist[2][T_STEPS][F_INPUT];      // 32 KB
    float* hcol = &hist[half_id][0][f];
#pragma unroll
    for (int t = 0; t < T_STEPS; ++t) hcol[t * F_INPUT] = 0.0f;

    const float denom = mx - mn + 1e-8f;
    for (int s = 0; s < S_SZ; ++s) {
        float val = xp[(size_t)s * F_INPUT];
        float g = (val < 0.75f) ? 0.0f : val;
        float xn = (g - mn) / denom;
        float d  = fmaxf(xn, 0.0100001f);            // clip(xn, LAT_THR+EPS)
        float tt = logf(d / (d - 0.01f));            // log latency code
        tt = tt * 31.0f;
        tt = tt / 11.512935464920229f;               // float32(log((thr+eps)/eps))
        float tr = rintf(tt);                        // half-to-even == jnp.round
        tr = fminf(fmaxf(tr, 0.0f), 31.0f);
        hcol[(int)tr * F_INPUT] += 1.0f;
    }

    // b-major: row = b*32 + t
    half_t* rp = rates + (size_t)b * T_STEPS * F_INPUT + f;
#pragma unroll
    for (int t = 0; t < T_STEPS; ++t)
        rp[(size_t)t * F_INPUT] = (half_t)(hcol[t * F_INPUT] * 0.015625f);
}

// ---------------------------------------------------------------------------
// Kernel 2: FUSED MFMA GEMM + LIF scan.
// GEMM: C[m][n] = sum A*hi + 2^-12 * sum A*lo + bias  (dual accumulator,
// pre-split f16 weights — exact to fp32-reorder noise; absmax 0 in R3/R4).
// Block tile 128x64, 4 waves 2x2, wave tile 64x32, BK=64 halfs.
// M rows are b-major (m = b*32 + t): the tile holds 4 full t-sequences.
// Epilogue: cur tile -> LDS (reuses staging LDS), 256 threads scan one
// (b,h) column each over t=0..31, emit spikes:
//   FINAL=0: f16 spikes in next layer's A layout [b*32+t][n]
//   FINAL=1: f32 spikes to d_out in reference layout [t*512+b][n]
// ---------------------------------------------------------------------------
#define BM   128
#define BN   64
#define BKH  64     // original-K halfs per stage
#define LDA  72     // As row stride (halfs)
#define LDW  136    // Ws row stride (halfs) = 2*BKH + 8
#define LDC  68     // cur tile row stride (floats)

template<int FINAL>
__global__ __launch_bounds__(256)
void gemm_lif_kernel(const half_t* __restrict__ A,
                     const half_t* __restrict__ Whl,
                     const float*  __restrict__ bias,
                     half_t* __restrict__ spk_next,
                     float*  __restrict__ out_final,
                     int M, int N, int K) {
    // GEMM phase needs 18432 + 17408 = 35840 B; scan phase 128*68*4 = 34816 B.
    __shared__ __align__(16) char smem[36352];
    half_t* As   = (half_t*)smem;             // [BM][LDA]
    half_t* Ws   = (half_t*)(smem + 18432);   // [BN][LDW]
    float*  curT = (float*)smem;              // [BM][LDC]  (aliases As/Ws)

    const int tid  = threadIdx.x;
    const int m0   = blockIdx.x * BM;
    const int n0   = blockIdx.y * BN;
    const int wave = tid >> 6;
    const int lane = tid & 63;
    const int wm   = (wave >> 1) * 64;
    const int wn   = (wave & 1) * 32;
    const int quad = lane >> 4;
    const int lr   = lane & 15;
    const int K2   = 2 * K;

    float4v acc_h[4][2], acc_l[4][2];
#pragma unroll
    for (int i = 0; i < 4; ++i)
#pragma unroll
        for (int j = 0; j < 2; ++j) {
            acc_h[i][j] = (float4v){0.0f, 0.0f, 0.0f, 0.0f};
            acc_l[i][j] = (float4v){0.0f, 0.0f, 0.0f, 0.0f};
        }

    const int arow = tid >> 3;           // A staging: 4 rows/thread (+32*i)
    const int aoff = (tid & 7) * 8;
    const int wrow = tid >> 4;           // W staging: 4 rows/thread (+16*i)
    const int woff = (tid & 15) * 8;

    for (int k0 = 0; k0 < K; k0 += BKH) {
#pragma unroll
        for (int i = 0; i < 4; ++i) {
            int r = arow + i * 32;
            *(uint4*)(&As[r * LDA + aoff]) =
                *(const uint4*)(A + (size_t)(m0 + r) * K + k0 + aoff);
        }
#pragma unroll
        for (int i = 0; i < 4; ++i) {
            int r = wrow + i * 16;
            *(uint4*)(&Ws[r * LDW + woff]) =
                *(const uint4*)(Whl + (size_t)(n0 + r) * K2 + 2 * k0 + woff);
        }
        __syncthreads();

#pragma unroll
        for (int kk = 0; kk < 2; ++kk) {
            half8 af[4], wh[2], wl[2];
#pragma unroll
            for (int mt = 0; mt < 4; ++mt)
                af[mt] = *(const half8*)(&As[(wm + mt * 16 + lr) * LDA + kk * 32 + quad * 8]);
#pragma unroll
            for (int nt = 0; nt < 2; ++nt) {
                const half_t* wp = &Ws[(wn + nt * 16 + lr) * LDW + kk * 64 + quad * 8];
                wh[nt] = *(const half8*)(wp);
                wl[nt] = *(const half8*)(wp + 32);
            }
#pragma unroll
            for (int mt = 0; mt < 4; ++mt)
#pragma unroll
                for (int nt = 0; nt < 2; ++nt) {
                    acc_h[mt][nt] = __builtin_amdgcn_mfma_f32_16x16x32_f16(
                        af[mt], wh[nt], acc_h[mt][nt], 0, 0, 0);
                    acc_l[mt][nt] = __builtin_amdgcn_mfma_f32_16x16x32_f16(
                        af[mt], wl[nt], acc_l[mt][nt], 0, 0, 0);
                }
        }
        __syncthreads();   // also fences As/Ws before curT aliases them
    }

    // ---- epilogue: cur tile into LDS (C/D layout: col=lane&15, row=quad*4+r)
#pragma unroll
    for (int nt = 0; nt < 2; ++nt) {
        int nl = wn + nt * 16 + lr;              // local col
        float bj = bias[n0 + nl];
#pragma unroll
        for (int mt = 0; mt < 4; ++mt) {
            int rbase = wm + mt * 16 + quad * 4; // local row
#pragma unroll
            for (int r = 0; r < 4; ++r) {
                float v = acc_h[mt][nt][r] + 2.44140625e-04f * acc_l[mt][nt][r];
                curT[(rbase + r) * LDC + nl] = v + bj;
            }
        }
    }
    __syncthreads();

    // ---- LIF scan: thread (bl,h) scans t=0..31. fp contract OFF: the
    // reference does separate mul/add/sub; fma changes threshold rounding.
    {
#pragma clang fp contract(off)
        const int bl = tid >> 6;                 // 0..3 local batch
        const int h  = tid & 63;                 // local col
        const int bglob = (m0 >> 5) + bl;        // global batch
        float mem = 0.0f;
#pragma unroll
        for (int t = 0; t < T_STEPS; ++t) {
            float c = curT[(bl * 32 + t) * LDC + h];
            float reset = (mem - 1.0f > 0.0f) ? 1.0f : 0.0f;
            float p = 0.9f * mem;
            p = p + c;
            mem = p - reset;
            float s = (mem - 1.0f > 0.0f) ? 1.0f : 0.0f;
            if (FINAL) {
                // d_out layout [t*B + b][h], f32; 256 B/wave contiguous
                out_final[((size_t)t * B_SZ + bglob) * N + n0 + h] = s;
            } else {
                // next A layout [b*32 + t][n], f16; 128 B/wave contiguous
                spk_next[((size_t)bglob * T_STEPS + t) * N + n0 + h] = (half_t)s;
            }
        }
    }
}

// ---------------------------------------------------------------------------
extern "C" void kernel_launch(void* const* d_in, const int* in_sizes, int n_in,
                              void* d_out, int out_size, void* d_ws, size_t ws_size,
                              hipStream_t stream) {
    const float* x  = (const float*)d_in[0];
    const float* W1 = (const float*)d_in[1];
    const float* b1 = (const float*)d_in[2];
    const float* W2 = (const float*)d_in[3];
    const float* b2 = (const float*)d_in[4];
    const float* W3 = (const float*)d_in[5];
    const float* b3 = (const float*)d_in[6];
    float* out = (float*)d_out;

    char* ws = (char*)d_ws;
    half_t* A0   = (half_t*)ws;                                  // 8 MB
    half_t* A1   = (half_t*)(ws + (size_t) 8 * 1024 * 1024);     // 8 MB
    half_t* whl1 = (half_t*)(ws + (size_t)16 * 1024 * 1024);     // 128 KB
    half_t* whl2 = (half_t*)(ws + (size_t)17 * 1024 * 1024);     // 256 KB
    half_t* whl3 = (half_t*)(ws + (size_t)18 * 1024 * 1024);     // 128 KB

    const int M = T_STEPS * B_SZ;   // 16384

    // 0. split weights (one dispatch, all layers)
    prep_w_kernel<<<(H1 * F_INPUT + H2 * H1 + H3 * H2) / 256, 256, 0, stream>>>(
        W1, W2, W3, whl1, whl2, whl3);

    // 1. encode: x -> rates f16, b-major (M x 128) in A0
    encode_kernel<<<B_SZ / 2, 256, 0, stream>>>(x, A0);

    // 2. layer 1 fused: spikes f16 -> A1
    gemm_lif_kernel<0><<<dim3(M / BM, H1 / BN), 256, 0, stream>>>(
        A0, whl1, b1, A1, nullptr, M, H1, F_INPUT);

    // 3. layer 2 fused: spikes f16 -> A0
    gemm_lif_kernel<0><<<dim3(M / BM, H2 / BN), 256, 0, stream>>>(
        A1, whl2, b2, A0, nullptr, M, H2, H1);

    // 4. layer 3 fused: spikes f32 -> d_out (reference layout [t*B+b][h])
    gemm_lif_kernel<1><<<dim3(M / BM, H3 / BN), 256, 0, stream>>>(
        A0, whl3, b3, nullptr, out, M, H3, H2);
}

// Round 6
// 102.562 us; speedup vs baseline: 1.9750x; 1.1550x over previous
//
#include <hip/hip_runtime.h>
#include <cstddef>

// Problem constants (match reference)
#define T_STEPS 32
#define B_SZ    512
#define S_SZ    64
#define F_INPUT 128
#define H1      256
#define H2      256
#define H3      128

typedef _Float16 half_t;
typedef __attribute__((ext_vector_type(8))) _Float16 half8;
typedef __attribute__((ext_vector_type(4))) float   float4v;

// ---------------------------------------------------------------------------
// Kernel 0: pre-split + SWIZZLE weights into MFMA-fragment order.
//   hi = f16(w) (flushed if f16-denormal), lo = f16((w - hi) * 2^12)
// Layout: tile (n_tile, k_chunk) = 1024 halfs at ((n_tile*kchunks + k_chunk)*1024):
//   [0..512):  hi, element (lr=n&15, quad=kin>>3, j=kin&7) at (quad*16+lr)*8 + j
//   [512..1024): lo, same order.
// A wave's B-frag load is then base + lane*8 -> 1 KB fully coalesced (L2-hot).
// ---------------------------------------------------------------------------
__device__ inline void split_store_sw(float w, half_t* out, int n, int k, int kchunks) {
    half_t hi = (half_t)w;
    float hif = (float)hi;
    if (fabsf(hif) < 6.103515625e-05f) { hi = (half_t)0.0f; hif = 0.0f; }
    half_t lo = (half_t)((w - hif) * 4096.0f);
    int n_tile = n >> 4, lr = n & 15;
    int k_chunk = k >> 5, kin = k & 31, quad = kin >> 3, j = kin & 7;
    size_t base = (size_t)(n_tile * kchunks + k_chunk) * 1024;
    size_t off  = base + (size_t)((quad << 4) + lr) * 8 + j;
    out[off]       = hi;
    out[off + 512] = lo;
}

__global__ __launch_bounds__(256)
void prep_w_kernel(const float* __restrict__ W1, const float* __restrict__ W2,
                   const float* __restrict__ W3,
                   half_t* __restrict__ ws1, half_t* __restrict__ ws2,
                   half_t* __restrict__ ws3) {
    int e = blockIdx.x * blockDim.x + threadIdx.x;   // 0..131071
    if (e < H1 * F_INPUT) {                          // 256 x 128, kchunks=4
        split_store_sw(W1[e], ws1, e / F_INPUT, e % F_INPUT, F_INPUT / 32);
    } else if (e < H1 * F_INPUT + H2 * H1) {         // 256 x 256, kchunks=8
        int i = e - H1 * F_INPUT;
        split_store_sw(W2[i], ws2, i / H1, i % H1, H1 / 32);
    } else {                                         // 128 x 256, kchunks=8
        int i = e - H1 * F_INPUT - H2 * H1;
        split_store_sw(W3[i], ws3, i / H2, i % H2, H2 / 32);
    }
}

// ---------------------------------------------------------------------------
// LDS geometry for the mega kernel (per block = one batch = 32 t-rows)
// ---------------------------------------------------------------------------
#define CUR_STRIDE 260   // floats; cur tile [32][CUR_STRIDE]
#define AS_STRIDE  136   // halfs;  rates   [32][AS_STRIDE]
#define SPK_STRIDE 264   // halfs;  spikes  [32][SPK_STRIDE]
#define SMEM_CUR   0                      // 32*260*4 = 33280 B (aliases hist)
#define SMEM_AS    33280                  // 32*136*2 =  8704 B
#define SMEM_SPK   41984                  // 32*264*2 = 16896 B
#define SMEM_TOTAL 58880                  // < 64 KB; 2 blocks/CU = 117.8 KB

// GEMM phase: C[m][n] = sum_k A[m][k]*(hi + 2^-12 lo)[n][k] + bias[n]
// A in LDS (ASTRIDE row pitch), W swizzled from global (L2), cur -> LDS.
// Wave tile 32 x (NT*16). NO barriers inside the K-loop.
template<int KCHUNKS, int NT, int ASTRIDE>
__device__ __forceinline__ void gemm_phase(const half_t* __restrict__ Wsw,
                                           const half_t* __restrict__ Als,
                                           const float*  __restrict__ bias,
                                           float* __restrict__ curT,
                                           int wave, int lane) {
    const int quad = lane >> 4, lr = lane & 15;
    float4v acc_h[2][NT], acc_l[2][NT];
#pragma unroll
    for (int mt = 0; mt < 2; ++mt)
#pragma unroll
        for (int nt = 0; nt < NT; ++nt) {
            acc_h[mt][nt] = (float4v){0.0f, 0.0f, 0.0f, 0.0f};
            acc_l[mt][nt] = (float4v){0.0f, 0.0f, 0.0f, 0.0f};
        }

#pragma unroll
    for (int c = 0; c < KCHUNKS; ++c) {
        half8 a0 = *(const half8*)(Als + lr * ASTRIDE        + c * 32 + quad * 8);
        half8 a1 = *(const half8*)(Als + (16 + lr) * ASTRIDE + c * 32 + quad * 8);
        half8 wh[NT], wl[NT];
#pragma unroll
        for (int nt = 0; nt < NT; ++nt) {
            const half_t* base =
                Wsw + (size_t)((wave * NT + nt) * KCHUNKS + c) * 1024 + lane * 8;
            wh[nt] = *(const half8*)(base);
            wl[nt] = *(const half8*)(base + 512);
        }
#pragma unroll
        for (int nt = 0; nt < NT; ++nt) {
            acc_h[0][nt] = __builtin_amdgcn_mfma_f32_16x16x32_f16(a0, wh[nt], acc_h[0][nt], 0, 0, 0);
            acc_l[0][nt] = __builtin_amdgcn_mfma_f32_16x16x32_f16(a0, wl[nt], acc_l[0][nt], 0, 0, 0);
            acc_h[1][nt] = __builtin_amdgcn_mfma_f32_16x16x32_f16(a1, wh[nt], acc_h[1][nt], 0, 0, 0);
            acc_l[1][nt] = __builtin_amdgcn_mfma_f32_16x16x32_f16(a1, wl[nt], acc_l[1][nt], 0, 0, 0);
        }
    }

    // epilogue -> curT (C/D layout: col=lane&15, row=quad*4+reg)
#pragma unroll
    for (int nt = 0; nt < NT; ++nt) {
        int col = wave * NT * 16 + nt * 16 + lr;
        float bj = bias[col];
#pragma unroll
        for (int mt = 0; mt < 2; ++mt) {
            int rbase = mt * 16 + quad * 4;
#pragma unroll
            for (int r = 0; r < 4; ++r) {
                float v = acc_h[mt][nt][r] + 2.44140625e-04f * acc_l[mt][nt][r];
                curT[(rbase + r) * CUR_STRIDE + col] = v + bj;
            }
        }
    }
}

// ---------------------------------------------------------------------------
// Mega kernel: one block = one batch b. encode -> L1 -> LIF -> L2 -> LIF ->
// L3 -> LIF -> d_out. Spikes never touch HBM.
// ---------------------------------------------------------------------------
__global__ __launch_bounds__(256, 2)
void snn_mega_kernel(const float* __restrict__ x,
                     const half_t* __restrict__ ws1, const float* __restrict__ b1,
                     const half_t* __restrict__ ws2, const float* __restrict__ b2,
                     const half_t* __restrict__ ws3, const float* __restrict__ b3,
                     float* __restrict__ out) {
    __shared__ __align__(16) char smem[SMEM_TOTAL];
    float*  curT = (float*) (smem + SMEM_CUR);   // also hist/minmax scratch
    half_t* As   = (half_t*)(smem + SMEM_AS);
    half_t* spk  = (half_t*)(smem + SMEM_SPK);

    const int tid  = threadIdx.x;
    const int b    = blockIdx.x;
    const int wave = tid >> 6;
    const int lane = tid & 63;

    // ================= phase 0: latency encode =================
    {
        const int f  = tid & 127;
        const int sh = tid >> 7;                 // s-half: 0 -> s 0..31, 1 -> 32..63
        const float* xp = x + (size_t)b * (S_SZ * F_INPUT) + (size_t)sh * 32 * F_INPUT + f;
        float* scratch = curT;                   // reuse region

        float mn = 1e30f, mx = -1e30f;
        for (int s = 0; s < 32; ++s) {
            float val = xp[(size_t)s * F_INPUT];
            float g = (val < 0.75f) ? 0.0f : val;    // gate at ENC_THR
            mn = fminf(mn, g);
            mx = fmaxf(mx, g);
        }
        scratch[sh * 128 + f]       = mn;
        scratch[256 + sh * 128 + f] = mx;
        __syncthreads();
        // exact: min(min(s0..31), min(s32..63)) == min(all)
        float fmn = fminf(scratch[f], scratch[128 + f]);
        float fmx = fmaxf(scratch[256 + f], scratch[384 + f]);
        __syncthreads();

        float* hist = scratch;                   // hist[2][32][128]
        for (int t = 0; t < T_STEPS; ++t) hist[sh * 4096 + t * 128 + f] = 0.0f;
        // no barrier needed: each thread touches only its own (sh, *, f) cells

        const float denom = fmx - fmn + 1e-8f;
        for (int s = 0; s < 32; ++s) {
            float val = xp[(size_t)s * F_INPUT];
            float g = (val < 0.75f) ? 0.0f : val;
            float xn = (g - fmn) / denom;
            float d  = fmaxf(xn, 0.0100001f);        // clip(xn, LAT_THR+EPS)
            float tt = logf(d / (d - 0.01f));        // log latency code
            tt = tt * 31.0f;
            tt = tt / 11.512935464920229f;           // float32(log((thr+eps)/eps))
            float tr = rintf(tt);                    // half-to-even == jnp.round
            tr = fminf(fmaxf(tr, 0.0f), 31.0f);
            hist[sh * 4096 + (int)tr * 128 + f] += 1.0f;
        }
        __syncthreads();

        // merge halves, write rates (exact k/64) into As[t][f]
        for (int i = 0; i < 16; ++i) {
            int idx = tid + i * 256;                 // 0..4095
            int t = idx >> 7, ff = idx & 127;
            float cnt = hist[t * 128 + ff] + hist[4096 + t * 128 + ff];
            As[t * AS_STRIDE + ff] = (half_t)(cnt * 0.015625f);
        }
        __syncthreads();
    }

    // ================= layer 1: GEMM (K=128) + LIF =================
    gemm_phase<F_INPUT / 32, 4, AS_STRIDE>(ws1, As, b1, curT, wave, lane);
    __syncthreads();
    {
#pragma clang fp contract(off)
        const int h = tid;                           // 256 cols
        float mem = 0.0f;
#pragma unroll
        for (int t = 0; t < T_STEPS; ++t) {
            float c = curT[t * CUR_STRIDE + h];
            float reset = (mem - 1.0f > 0.0f) ? 1.0f : 0.0f;
            float p = 0.9f * mem;
            p = p + c;
            mem = p - reset;
            spk[t * SPK_STRIDE + h] = (half_t)((mem - 1.0f > 0.0f) ? 1.0f : 0.0f);
        }
    }
    __syncthreads();

    // ================= layer 2: GEMM (K=256) + LIF =================
    gemm_phase<H1 / 32, 4, SPK_STRIDE>(ws2, spk, b2, curT, wave, lane);
    __syncthreads();
    {
#pragma clang fp contract(off)
        const int h = tid;
        float mem = 0.0f;
#pragma unroll
        for (int t = 0; t < T_STEPS; ++t) {
            float c = curT[t * CUR_STRIDE + h];
            float reset = (mem - 1.0f > 0.0f) ? 1.0f : 0.0f;
            float p = 0.9f * mem;
            p = p + c;
            mem = p - reset;
            spk[t * SPK_STRIDE + h] = (half_t)((mem - 1.0f > 0.0f) ? 1.0f : 0.0f);
        }
    }
    __syncthreads();

    // ================= layer 3: GEMM (K=256, N=128) + LIF -> out =========
    gemm_phase<H2 / 32, 2, SPK_STRIDE>(ws3, spk, b3, curT, wave, lane);
    __syncthreads();
    if (tid < H3) {
#pragma clang fp contract(off)
        const int h = tid;
        float mem = 0.0f;
#pragma unroll
        for (int t = 0; t < T_STEPS; ++t) {
            float c = curT[t * CUR_STRIDE + h];
            float reset = (mem - 1.0f > 0.0f) ? 1.0f : 0.0f;
            float p = 0.9f * mem;
            p = p + c;
            mem = p - reset;
            // reference output layout: [t*B + b][h], f32
            out[((size_t)t * B_SZ + b) * H3 + h] = (mem - 1.0f > 0.0f) ? 1.0f : 0.0f;
        }
    }
}

// ---------------------------------------------------------------------------
extern "C" void kernel_launch(void* const* d_in, const int* in_sizes, int n_in,
                              void* d_out, int out_size, void* d_ws, size_t ws_size,
                              hipStream_t stream) {
    const float* x  = (const float*)d_in[0];
    const float* W1 = (const float*)d_in[1];
    const float* b1 = (const float*)d_in[2];
    const float* W2 = (const float*)d_in[3];
    const float* b2 = (const float*)d_in[4];
    const float* W3 = (const float*)d_in[5];
    const float* b3 = (const float*)d_in[6];
    float* out = (float*)d_out;

    char* ws = (char*)d_ws;
    half_t* ws1 = (half_t*)ws;                          // 128 KB (swizzled hi/lo)
    half_t* ws2 = (half_t*)(ws + 128 * 1024);           // 256 KB
    half_t* ws3 = (half_t*)(ws + 384 * 1024);           // 128 KB

    // 0. split + swizzle weights (one dispatch, all layers)
    prep_w_kernel<<<(H1 * F_INPUT + H2 * H1 + H3 * H2) / 256, 256, 0, stream>>>(
        W1, W2, W3, ws1, ws2, ws3);

    // 1. whole network: one block per batch, spikes stay in LDS
    snn_mega_kernel<<<B_SZ, 256, 0, stream>>>(x, ws1, b1, ws2, b2, ws3, b3, out);
}

// Round 7
// 99.785 us; speedup vs baseline: 2.0300x; 1.0278x over previous
//
#include <hip/hip_runtime.h>
#include <cstddef>

// Problem constants (match reference)
#define T_STEPS 32
#define B_SZ    512
#define S_SZ    64
#define F_INPUT 128
#define H1      256
#define H2      256
#define H3      128

typedef _Float16 half_t;
typedef __attribute__((ext_vector_type(8))) _Float16 half8;
typedef __attribute__((ext_vector_type(4))) float   float4v;

// ---------------------------------------------------------------------------
// Kernel 0: pre-split + SWIZZLE weights into MFMA-fragment order (unchanged
// from R6 — verified exact).
//   hi = f16(w) (flushed if f16-denormal), lo = f16((w - hi) * 2^12)
// Tile (n_tile, k_chunk) = 1024 halfs: [0,512) hi, [512,1024) lo, element
// (lr=n&15, quad=kin>>3, j=kin&7) at (quad*16+lr)*8 + j.
// Wave B-frag load = base + lane*8 -> 1 KB fully coalesced, L2-resident.
// ---------------------------------------------------------------------------
__device__ inline void split_store_sw(float w, half_t* out, int n, int k, int kchunks) {
    half_t hi = (half_t)w;
    float hif = (float)hi;
    if (fabsf(hif) < 6.103515625e-05f) { hi = (half_t)0.0f; hif = 0.0f; }
    half_t lo = (half_t)((w - hif) * 4096.0f);
    int n_tile = n >> 4, lr = n & 15;
    int k_chunk = k >> 5, kin = k & 31, quad = kin >> 3, j = kin & 7;
    size_t base = (size_t)(n_tile * kchunks + k_chunk) * 1024;
    size_t off  = base + (size_t)((quad << 4) + lr) * 8 + j;
    out[off]       = hi;
    out[off + 512] = lo;
}

__global__ __launch_bounds__(256)
void prep_w_kernel(const float* __restrict__ W1, const float* __restrict__ W2,
                   const float* __restrict__ W3,
                   half_t* __restrict__ ws1, half_t* __restrict__ ws2,
                   half_t* __restrict__ ws3) {
    int e = blockIdx.x * blockDim.x + threadIdx.x;   // 0..131071
    if (e < H1 * F_INPUT) {                          // 256 x 128, kchunks=4
        split_store_sw(W1[e], ws1, e / F_INPUT, e % F_INPUT, F_INPUT / 32);
    } else if (e < H1 * F_INPUT + H2 * H1) {         // 256 x 256, kchunks=8
        int i = e - H1 * F_INPUT;
        split_store_sw(W2[i], ws2, i / H1, i % H1, H1 / 32);
    } else {                                         // 128 x 256, kchunks=8
        int i = e - H1 * F_INPUT - H2 * H1;
        split_store_sw(W3[i], ws3, i / H2, i % H2, H2 / 32);
    }
}

// ---------------------------------------------------------------------------
// LDS geometry. CHANGED vs R6: spk aliases As (As dead after L1 K-loop) —
// 58.9 KB -> 49 KB, so 512-thread blocks fit 2/CU = 4 waves/SIMD (R6 ran
// 2 waves/SIMD and was latency-bound: mega ~50us vs ~13us arithmetic floor).
// ---------------------------------------------------------------------------
#define CUR_STRIDE 260   // floats; cur tile [32][CUR_STRIDE] (also hist scratch)
#define AS_STRIDE  136   // halfs;  rates  [32][AS_STRIDE]
#define SPK_STRIDE 264   // halfs;  spikes [32][SPK_STRIDE]
#define SMEM_CUR   0                      // 32*260*4 = 33280 B
#define SMEM_AS    33280                  // As: 8704 B  } aliased: max = 16896
#define SMEM_SPK   33280                  // spk: 16896 B}
#define SMEM_TOTAL 50176                  // 49 KB; x2 blocks/CU = 98 KB < 160

// GEMM phase: C[m][n] = sum_k A[m][k]*(hi + 2^-12 lo)[n][k] + bias[n]
// A in LDS, W swizzled from global (L2), cur -> LDS. 8 waves, wave tile
// 32 x (NT*16). NO barriers inside the K-loop. Per-accumulator reduction
// order identical to R6 (bit-exact, absmax 0).
template<int KCHUNKS, int NT, int ASTRIDE>
__device__ __forceinline__ void gemm_phase(const half_t* __restrict__ Wsw,
                                           const half_t* __restrict__ Als,
                                           const float*  __restrict__ bias,
                                           float* __restrict__ curT,
                                           int wave, int lane) {
    const int quad = lane >> 4, lr = lane & 15;
    float4v acc_h[2][NT], acc_l[2][NT];
#pragma unroll
    for (int mt = 0; mt < 2; ++mt)
#pragma unroll
        for (int nt = 0; nt < NT; ++nt) {
            acc_h[mt][nt] = (float4v){0.0f, 0.0f, 0.0f, 0.0f};
            acc_l[mt][nt] = (float4v){0.0f, 0.0f, 0.0f, 0.0f};
        }

#pragma unroll
    for (int c = 0; c < KCHUNKS; ++c) {
        half8 a0 = *(const half8*)(Als + lr * ASTRIDE        + c * 32 + quad * 8);
        half8 a1 = *(const half8*)(Als + (16 + lr) * ASTRIDE + c * 32 + quad * 8);
        half8 wh[NT], wl[NT];
#pragma unroll
        for (int nt = 0; nt < NT; ++nt) {
            const half_t* base =
                Wsw + (size_t)((wave * NT + nt) * KCHUNKS + c) * 1024 + lane * 8;
            wh[nt] = *(const half8*)(base);
            wl[nt] = *(const half8*)(base + 512);
        }
#pragma unroll
        for (int nt = 0; nt < NT; ++nt) {
            acc_h[0][nt] = __builtin_amdgcn_mfma_f32_16x16x32_f16(a0, wh[nt], acc_h[0][nt], 0, 0, 0);
            acc_l[0][nt] = __builtin_amdgcn_mfma_f32_16x16x32_f16(a0, wl[nt], acc_l[0][nt], 0, 0, 0);
            acc_h[1][nt] = __builtin_amdgcn_mfma_f32_16x16x32_f16(a1, wh[nt], acc_h[1][nt], 0, 0, 0);
            acc_l[1][nt] = __builtin_amdgcn_mfma_f32_16x16x32_f16(a1, wl[nt], acc_l[1][nt], 0, 0, 0);
        }
    }

    // epilogue -> curT (C/D layout: col=lane&15, row=quad*4+reg)
#pragma unroll
    for (int nt = 0; nt < NT; ++nt) {
        int col = wave * NT * 16 + nt * 16 + lr;
        float bj = bias[col];
#pragma unroll
        for (int mt = 0; mt < 2; ++mt) {
            int rbase = mt * 16 + quad * 4;
#pragma unroll
            for (int r = 0; r < 4; ++r) {
                float v = acc_h[mt][nt][r] + 2.44140625e-04f * acc_l[mt][nt][r];
                curT[(rbase + r) * CUR_STRIDE + col] = v + bj;
            }
        }
    }
}

// ---------------------------------------------------------------------------
// Mega kernel: one block = one batch b, 512 threads (8 waves).
// encode -> L1 -> LIF -> L2 -> LIF -> L3 -> LIF -> out; spikes stay in LDS.
// All __syncthreads at top level (encode/scan bodies are tid-gated but
// barrier-free inside).
// ---------------------------------------------------------------------------
__global__ __launch_bounds__(512, 4)
void snn_mega_kernel(const float* __restrict__ x,
                     const half_t* __restrict__ ws1, const float* __restrict__ b1,
                     const half_t* __restrict__ ws2, const float* __restrict__ b2,
                     const half_t* __restrict__ ws3, const float* __restrict__ b3,
                     float* __restrict__ out) {
    __shared__ __align__(16) char smem[SMEM_TOTAL];
    float*  curT = (float*) (smem + SMEM_CUR);   // also hist/minmax scratch
    half_t* As   = (half_t*)(smem + SMEM_AS);    // aliases spk (As dead first)
    half_t* spk  = (half_t*)(smem + SMEM_SPK);

    const int tid  = threadIdx.x;
    const int b    = blockIdx.x;
    const int wave = tid >> 6;
    const int lane = tid & 63;

    // ================= phase 0: latency encode (threads 0..255) ===========
    const int f  = tid & 127;
    const int sh = (tid >> 7) & 1;               // s-half: 0 -> s 0..31, 1 -> 32..63
    const float* xp = x + (size_t)b * (S_SZ * F_INPUT) + (size_t)sh * 32 * F_INPUT + f;
    float* scratch = curT;

    if (tid < 256) {
        float mn = 1e30f, mx = -1e30f;
        for (int s = 0; s < 32; ++s) {
            float val = xp[(size_t)s * F_INPUT];
            float g = (val < 0.75f) ? 0.0f : val;    // gate at ENC_THR
            mn = fminf(mn, g);
            mx = fmaxf(mx, g);
        }
        scratch[sh * 128 + f]       = mn;
        scratch[256 + sh * 128 + f] = mx;
    }
    __syncthreads();
    // exact: min(min half0, min half1) == min(all); same for max
    float fmn = fminf(scratch[f], scratch[128 + f]);
    float fmx = fmaxf(scratch[256 + f], scratch[384 + f]);
    __syncthreads();

    if (tid < 256) {
        float* hist = scratch;                   // hist[2][32][128] f32
        for (int t = 0; t < T_STEPS; ++t) hist[sh * 4096 + t * 128 + f] = 0.0f;
        // no barrier needed: each thread touches only its own (sh,*,f) cells
        const float denom = fmx - fmn + 1e-8f;
        for (int s = 0; s < 32; ++s) {
            float val = xp[(size_t)s * F_INPUT];
            float g = (val < 0.75f) ? 0.0f : val;
            float xn = (g - fmn) / denom;
            float d  = fmaxf(xn, 0.0100001f);        // clip(xn, LAT_THR+EPS)
            float tt = logf(d / (d - 0.01f));        // log latency code
            tt = tt * 31.0f;
            tt = tt / 11.512935464920229f;           // float32(log((thr+eps)/eps))
            float tr = rintf(tt);                    // half-to-even == jnp.round
            tr = fminf(fmaxf(tr, 0.0f), 31.0f);
            hist[sh * 4096 + (int)tr * 128 + f] += 1.0f;
        }
    }
    __syncthreads();

    // merge halves -> rates (exact k/64) into As[t][f]; all 512 threads
#pragma unroll
    for (int i = 0; i < 8; ++i) {
        int idx = tid + i * 512;                 // 0..4095
        int t = idx >> 7, ff = idx & 127;
        float cnt = scratch[t * 128 + ff] + scratch[4096 + t * 128 + ff];
        As[t * AS_STRIDE + ff] = (half_t)(cnt * 0.015625f);
    }
    __syncthreads();

    // ================= layer 1: GEMM (K=128, N=256) + LIF =================
    gemm_phase<F_INPUT / 32, 2, AS_STRIDE>(ws1, As, b1, curT, wave, lane);
    __syncthreads();   // all As reads done; spk may now overwrite As region
    if (tid < 256) {
#pragma clang fp contract(off)
        const int h = tid;
        float mem = 0.0f;
#pragma unroll
        for (int t = 0; t < T_STEPS; ++t) {
            float c = curT[t * CUR_STRIDE + h];
            float reset = (mem - 1.0f > 0.0f) ? 1.0f : 0.0f;
            float p = 0.9f * mem;
            p = p + c;
            mem = p - reset;
            spk[t * SPK_STRIDE + h] = (half_t)((mem - 1.0f > 0.0f) ? 1.0f : 0.0f);
        }
    }
    __syncthreads();

    // ================= layer 2: GEMM (K=256, N=256) + LIF =================
    gemm_phase<H1 / 32, 2, SPK_STRIDE>(ws2, spk, b2, curT, wave, lane);
    __syncthreads();
    if (tid < 256) {
#pragma clang fp contract(off)
        const int h = tid;
        float mem = 0.0f;
#pragma unroll
        for (int t = 0; t < T_STEPS; ++t) {
            float c = curT[t * CUR_STRIDE + h];
            float reset = (mem - 1.0f > 0.0f) ? 1.0f : 0.0f;
            float p = 0.9f * mem;
            p = p + c;
            mem = p - reset;
            spk[t * SPK_STRIDE + h] = (half_t)((mem - 1.0f > 0.0f) ? 1.0f : 0.0f);
        }
    }
    __syncthreads();

    // ================= layer 3: GEMM (K=256, N=128) + LIF -> out ==========
    gemm_phase<H2 / 32, 1, SPK_STRIDE>(ws3, spk, b3, curT, wave, lane);
    __syncthreads();
    if (tid < H3) {
#pragma clang fp contract(off)
        const int h = tid;
        float mem = 0.0f;
#pragma unroll
        for (int t = 0; t < T_STEPS; ++t) {
            float c = curT[t * CUR_STRIDE + h];
            float reset = (mem - 1.0f > 0.0f) ? 1.0f : 0.0f;
            float p = 0.9f * mem;
            p = p + c;
            mem = p - reset;
            // reference output layout: [t*B + b][h], f32
            out[((size_t)t * B_SZ + b) * H3 + h] = (mem - 1.0f > 0.0f) ? 1.0f : 0.0f;
        }
    }
}

// ---------------------------------------------------------------------------
extern "C" void kernel_launch(void* const* d_in, const int* in_sizes, int n_in,
                              void* d_out, int out_size, void* d_ws, size_t ws_size,
                              hipStream_t stream) {
    const float* x  = (const float*)d_in[0];
    const float* W1 = (const float*)d_in[1];
    const float* b1 = (const float*)d_in[2];
    const float* W2 = (const float*)d_in[3];
    const float* b2 = (const float*)d_in[4];
    const float* W3 = (const float*)d_in[5];
    const float* b3 = (const float*)d_in[6];
    float* out = (float*)d_out;

    char* ws = (char*)d_ws;
    half_t* ws1 = (half_t*)ws;                          // 128 KB (swizzled hi/lo)
    half_t* ws2 = (half_t*)(ws + 128 * 1024);           // 256 KB
    half_t* ws3 = (half_t*)(ws + 384 * 1024);           // 128 KB

    // 0. split + swizzle weights (one dispatch, all layers)
    prep_w_kernel<<<(H1 * F_INPUT + H2 * H1 + H3 * H2) / 256, 256, 0, stream>>>(
        W1, W2, W3, ws1, ws2, ws3);

    // 1. whole network: one block per batch, 8 waves, spikes stay in LDS
    snn_mega_kernel<<<B_SZ, 512, 0, stream>>>(x, ws1, b1, ws2, b2, ws3, b3, out);
}

// Round 9
// 99.515 us; speedup vs baseline: 2.0355x; 1.0027x over previous
//
#include <hip/hip_runtime.h>
#include <cstddef>

// Problem constants (match reference)
#define T_STEPS 32
#define B_SZ    512
#define S_SZ    64
#define F_INPUT 128
#define H1      256
#define H2      256
#define H3      128

typedef _Float16 half_t;
typedef __attribute__((ext_vector_type(8))) _Float16 half8;
typedef __attribute__((ext_vector_type(4))) float   float4v;

// ---------------------------------------------------------------------------
// Kernel 0: pre-split + SWIZZLE weights into MFMA-fragment order (unchanged
// from R6/R7 — verified exact).
//   hi = f16(w) (flushed if f16-denormal), lo = f16((w - hi) * 2^12)
// Tile (n_tile, k_chunk) = 1024 halfs: [0,512) hi, [512,1024) lo, element
// (lr=n&15, quad=kin>>3, j=kin&7) at (quad*16+lr)*8 + j.
// Wave B-frag load = base + lane*8 -> 1 KB fully coalesced, L2-resident.
// ---------------------------------------------------------------------------
__device__ inline void split_store_sw(float w, half_t* out, int n, int k, int kchunks) {
    half_t hi = (half_t)w;
    float hif = (float)hi;
    if (fabsf(hif) < 6.103515625e-05f) { hi = (half_t)0.0f; hif = 0.0f; }
    half_t lo = (half_t)((w - hif) * 4096.0f);
    int n_tile = n >> 4, lr = n & 15;
    int k_chunk = k >> 5, kin = k & 31, quad = kin >> 3, j = kin & 7;
    size_t base = (size_t)(n_tile * kchunks + k_chunk) * 1024;
    size_t off  = base + (size_t)((quad << 4) + lr) * 8 + j;
    out[off]       = hi;
    out[off + 512] = lo;
}

__global__ __launch_bounds__(256)
void prep_w_kernel(const float* __restrict__ W1, const float* __restrict__ W2,
                   const float* __restrict__ W3,
                   half_t* __restrict__ ws1, half_t* __restrict__ ws2,
                   half_t* __restrict__ ws3) {
    int e = blockIdx.x * blockDim.x + threadIdx.x;   // 0..131071
    if (e < H1 * F_INPUT) {                          // 256 x 128, kchunks=4
        split_store_sw(W1[e], ws1, e / F_INPUT, e % F_INPUT, F_INPUT / 32);
    } else if (e < H1 * F_INPUT + H2 * H1) {         // 256 x 256, kchunks=8
        int i = e - H1 * F_INPUT;
        split_store_sw(W2[i], ws2, i / H1, i % H1, H1 / 32);
    } else {                                         // 128 x 256, kchunks=8
        int i = e - H1 * F_INPUT - H2 * H1;
        split_store_sw(W3[i], ws3, i / H2, i % H2, H2 / 32);
    }
}

// ---------------------------------------------------------------------------
// LDS geometry (unchanged from R7): spk aliases As; 49 KB -> 2 blocks/CU.
// ---------------------------------------------------------------------------
#define CUR_STRIDE 260   // floats; cur tile [32][CUR_STRIDE] (also hist scratch)
#define AS_STRIDE  136   // halfs;  rates  [32][AS_STRIDE]
#define SPK_STRIDE 264   // halfs;  spikes [32][SPK_STRIDE]
#define SMEM_CUR   0                      // 32*260*4 = 33280 B
#define SMEM_AS    33280                  // As: 8704 B  } aliased: max = 16896
#define SMEM_SPK   33280                  // spk: 16896 B}
#define SMEM_TOTAL 50176                  // 49 KB; x2 blocks/CU = 98 KB < 160

// GEMM phase: C[m][n] = sum_k A[m][k]*(hi + 2^-12 lo)[n][k] + bias[n]
// Software-pipelined W prefetch (depth 1) with a small, bounded live set
// (~110 VGPR) so __launch_bounds__(512,4)'s 128-VGPR cap holds WITHOUT
// spills — R7's fully-hoisted loads wanted >128 and either spilled or
// dropped occupancy to 2 waves/SIMD (explaining its near-zero delta).
// Per-accumulator MFMA order unchanged -> bit-identical.
template<int KCHUNKS, int NT, int ASTRIDE>
__device__ __forceinline__ void gemm_phase(const half_t* __restrict__ Wsw,
                                           const half_t* __restrict__ bias_dummy_unused,
                                           const float*  __restrict__ bias,
                                           const half_t* __restrict__ Als,
                                           float* __restrict__ curT,
                                           int wave, int lane) {
    const int quad = lane >> 4, lr = lane & 15;
    float4v acc_h[2][NT], acc_l[2][NT];
#pragma unroll
    for (int mt = 0; mt < 2; ++mt)
#pragma unroll
        for (int nt = 0; nt < NT; ++nt) {
            acc_h[mt][nt] = (float4v){0.0f, 0.0f, 0.0f, 0.0f};
            acc_l[mt][nt] = (float4v){0.0f, 0.0f, 0.0f, 0.0f};
        }

    // preload chunk 0 W frags
    half8 wh[NT], wl[NT];
#pragma unroll
    for (int nt = 0; nt < NT; ++nt) {
        const half_t* p = Wsw + ((size_t)(wave * NT + nt) * KCHUNKS) * 1024 + lane * 8;
        wh[nt] = *(const half8*)(p);
        wl[nt] = *(const half8*)(p + 512);
    }

#pragma unroll
    for (int c = 0; c < KCHUNKS; ++c) {
        // a-frags for this chunk (LDS)
        half8 a0 = *(const half8*)(Als + lr * ASTRIDE        + c * 32 + quad * 8);
        half8 a1 = *(const half8*)(Als + (16 + lr) * ASTRIDE + c * 32 + quad * 8);
        // prefetch next chunk's W frags (in flight during this chunk's MFMAs)
        half8 nwh[NT], nwl[NT];
        if (c + 1 < KCHUNKS) {
#pragma unroll
            for (int nt = 0; nt < NT; ++nt) {
                const half_t* p =
                    Wsw + ((size_t)(wave * NT + nt) * KCHUNKS + c + 1) * 1024 + lane * 8;
                nwh[nt] = *(const half8*)(p);
                nwl[nt] = *(const half8*)(p + 512);
            }
        }
        // compute on current (resident) frags
#pragma unroll
        for (int nt = 0; nt < NT; ++nt) {
            acc_h[0][nt] = __builtin_amdgcn_mfma_f32_16x16x32_f16(a0, wh[nt], acc_h[0][nt], 0, 0, 0);
            acc_h[1][nt] = __builtin_amdgcn_mfma_f32_16x16x32_f16(a1, wh[nt], acc_h[1][nt], 0, 0, 0);
            acc_l[0][nt] = __builtin_amdgcn_mfma_f32_16x16x32_f16(a0, wl[nt], acc_l[0][nt], 0, 0, 0);
            acc_l[1][nt] = __builtin_amdgcn_mfma_f32_16x16x32_f16(a1, wl[nt], acc_l[1][nt], 0, 0, 0);
        }
#pragma unroll
        for (int nt = 0; nt < NT; ++nt) { wh[nt] = nwh[nt]; wl[nt] = nwl[nt]; }
    }

    // epilogue -> curT (C/D layout: col=lane&15, row=quad*4+reg)
#pragma unroll
    for (int nt = 0; nt < NT; ++nt) {
        int col = wave * NT * 16 + nt * 16 + lr;
        float bj = bias[col];
#pragma unroll
        for (int mt = 0; mt < 2; ++mt) {
            int rbase = mt * 16 + quad * 4;
#pragma unroll
            for (int r = 0; r < 4; ++r) {
                float v = acc_h[mt][nt][r] + 2.44140625e-04f * acc_l[mt][nt][r];
                curT[(rbase + r) * CUR_STRIDE + col] = v + bj;
            }
        }
    }
}

// ---------------------------------------------------------------------------
// Mega kernel: one block = one batch b, 512 threads (8 waves).
// encode -> L1 -> LIF -> L2 -> LIF -> L3 -> LIF -> out; spikes stay in LDS.
// ---------------------------------------------------------------------------
__global__ __launch_bounds__(512, 4)
void snn_mega_kernel(const float* __restrict__ x,
                     const half_t* __restrict__ ws1, const float* __restrict__ b1,
                     const half_t* __restrict__ ws2, const float* __restrict__ b2,
                     const half_t* __restrict__ ws3, const float* __restrict__ b3,
                     float* __restrict__ out) {
    __shared__ __align__(16) char smem[SMEM_TOTAL];
    float*  curT = (float*) (smem + SMEM_CUR);   // also hist/minmax scratch
    half_t* As   = (half_t*)(smem + SMEM_AS);    // aliases spk (As dead first)
    half_t* spk  = (half_t*)(smem + SMEM_SPK);

    const int tid  = threadIdx.x;
    const int b    = blockIdx.x;
    const int wave = tid >> 6;
    const int lane = tid & 63;

    // ================= phase 0: latency encode (threads 0..255) ===========
    const int f  = tid & 127;
    const int sh = (tid >> 7) & 1;               // s-half: 0 -> s 0..31, 1 -> 32..63
    const float* xp = x + (size_t)b * (S_SZ * F_INPUT) + (size_t)sh * 32 * F_INPUT + f;
    float* scratch = curT;

    if (tid < 256) {
        float mn = 1e30f, mx = -1e30f;
        for (int s = 0; s < 32; ++s) {
            float val = xp[(size_t)s * F_INPUT];
            float g = (val < 0.75f) ? 0.0f : val;    // gate at ENC_THR
            mn = fminf(mn, g);
            mx = fmaxf(mx, g);
        }
        scratch[sh * 128 + f]       = mn;
        scratch[256 + sh * 128 + f] = mx;
    }
    __syncthreads();
    // exact: min(min half0, min half1) == min(all); same for max
    float fmn = fminf(scratch[f], scratch[128 + f]);
    float fmx = fmaxf(scratch[256 + f], scratch[384 + f]);
    __syncthreads();

    if (tid < 256) {
        float* hist = scratch;                   // hist[2][32][128] f32
        for (int t = 0; t < T_STEPS; ++t) hist[sh * 4096 + t * 128 + f] = 0.0f;
        // no barrier needed: each thread touches only its own (sh,*,f) cells
        const float denom = fmx - fmn + 1e-8f;
        for (int s = 0; s < 32; ++s) {
            float val = xp[(size_t)s * F_INPUT];
            float g = (val < 0.75f) ? 0.0f : val;
            float xn = (g - fmn) / denom;
            float d  = fmaxf(xn, 0.0100001f);        // clip(xn, LAT_THR+EPS)
            float tt = logf(d / (d - 0.01f));        // log latency code
            tt = tt * 31.0f;
            tt = tt / 11.512935464920229f;           // float32(log((thr+eps)/eps))
            float tr = rintf(tt);                    // half-to-even == jnp.round
            tr = fminf(fmaxf(tr, 0.0f), 31.0f);
            hist[sh * 4096 + (int)tr * 128 + f] += 1.0f;
        }
    }
    __syncthreads();

    // merge halves -> rates (exact k/64) into As[t][f]; all 512 threads
#pragma unroll
    for (int i = 0; i < 8; ++i) {
        int idx = tid + i * 512;                 // 0..4095
        int t = idx >> 7, ff = idx & 127;
        float cnt = scratch[t * 128 + ff] + scratch[4096 + t * 128 + ff];
        As[t * AS_STRIDE + ff] = (half_t)(cnt * 0.015625f);
    }
    __syncthreads();

    // ================= layer 1: GEMM (K=128, N=256) + LIF =================
    gemm_phase<F_INPUT / 32, 2, AS_STRIDE>(ws1, nullptr, b1, As, curT, wave, lane);
    __syncthreads();   // all As reads done; spk may now overwrite As region
    if (tid < 256) {
#pragma clang fp contract(off)
        const int h = tid;
        float mem = 0.0f;
#pragma unroll
        for (int t = 0; t < T_STEPS; ++t) {
            float c = curT[t * CUR_STRIDE + h];
            float reset = (mem - 1.0f > 0.0f) ? 1.0f : 0.0f;
            float p = 0.9f * mem;
            p = p + c;
            mem = p - reset;
            spk[t * SPK_STRIDE + h] = (half_t)((mem - 1.0f > 0.0f) ? 1.0f : 0.0f);
        }
    }
    __syncthreads();

    // ================= layer 2: GEMM (K=256, N=256) + LIF =================
    gemm_phase<H1 / 32, 2, SPK_STRIDE>(ws2, nullptr, b2, spk, curT, wave, lane);
    __syncthreads();
    if (tid < 256) {
#pragma clang fp contract(off)
        const int h = tid;
        float mem = 0.0f;
#pragma unroll
        for (int t = 0; t < T_STEPS; ++t) {
            float c = curT[t * CUR_STRIDE + h];
            float reset = (mem - 1.0f > 0.0f) ? 1.0f : 0.0f;
            float p = 0.9f * mem;
            p = p + c;
            mem = p - reset;
            spk[t * SPK_STRIDE + h] = (half_t)((mem - 1.0f > 0.0f) ? 1.0f : 0.0f);
        }
    }
    __syncthreads();

    // ================= layer 3: GEMM (K=256, N=128) + LIF -> out ==========
    gemm_phase<H2 / 32, 1, SPK_STRIDE>(ws3, nullptr, b3, spk, curT, wave, lane);
    __syncthreads();
    if (tid < H3) {
#pragma clang fp contract(off)
        const int h = tid;
        float mem = 0.0f;
#pragma unroll
        for (int t = 0; t < T_STEPS; ++t) {
            float c = curT[t * CUR_STRIDE + h];
            float reset = (mem - 1.0f > 0.0f) ? 1.0f : 0.0f;
            float p = 0.9f * mem;
            p = p + c;
            mem = p - reset;
            // reference output layout: [t*B + b][h], f32
            out[((size_t)t * B_SZ + b) * H3 + h] = (mem - 1.0f > 0.0f) ? 1.0f : 0.0f;
        }
    }
}

// ---------------------------------------------------------------------------
extern "C" void kernel_launch(void* const* d_in, const int* in_sizes, int n_in,
                              void* d_out, int out_size, void* d_ws, size_t ws_size,
                              hipStream_t stream) {
    const float* x  = (const float*)d_in[0];
    const float* W1 = (const float*)d_in[1];
    const float* b1 = (const float*)d_in[2];
    const float* W2 = (const float*)d_in[3];
    const float* b2 = (const float*)d_in[4];
    const float* W3 = (const float*)d_in[5];
    const float* b3 = (const float*)d_in[6];
    float* out = (float*)d_out;

    char* ws = (char*)d_ws;
    half_t* ws1 = (half_t*)ws;                          // 128 KB (swizzled hi/lo)
    half_t* ws2 = (half_t*)(ws + 128 * 1024);           // 256 KB
    half_t* ws3 = (half_t*)(ws + 384 * 1024);           // 128 KB

    // 0. split + swizzle weights (one dispatch, all layers)
    prep_w_kernel<<<(H1 * F_INPUT + H2 * H1 + H3 * H2) / 256, 256, 0, stream>>>(
        W1, W2, W3, ws1, ws2, ws3);

    // 1. whole network: one block per batch, 8 waves, spikes stay in LDS
    snn_mega_kernel<<<B_SZ, 512, 0, stream>>>(x, ws1, b1, ws2, b2, ws3, b3, out);
}

// Round 10
// 96.826 us; speedup vs baseline: 2.0920x; 1.0278x over previous
//
#include <hip/hip_runtime.h>
#include <cstddef>

// Problem constants (match reference)
#define T_STEPS 32
#define B_SZ    512
#define S_SZ    64
#define F_INPUT 128
#define H1      256
#define H2      256
#define H3      128

typedef _Float16 half_t;
typedef __attribute__((ext_vector_type(8))) _Float16 half8;
typedef __attribute__((ext_vector_type(4))) float   float4v;

// ---------------------------------------------------------------------------
// Kernel 0: pre-split + SWIZZLE weights into MFMA-fragment order (unchanged
// from R6..R9 — verified exact).
//   hi = f16(w) (flushed if f16-denormal), lo = f16((w - hi) * 2^12)
// Tile (n_tile, k_chunk) = 1024 halfs: [0,512) hi, [512,1024) lo, element
// (lr=n&15, quad=kin>>3, j=kin&7) at (quad*16+lr)*8 + j.
// Wave B-frag load = base + lane*8 -> 1 KB fully coalesced, L2-resident.
// ---------------------------------------------------------------------------
__device__ inline void split_store_sw(float w, half_t* out, int n, int k, int kchunks) {
    half_t hi = (half_t)w;
    float hif = (float)hi;
    if (fabsf(hif) < 6.103515625e-05f) { hi = (half_t)0.0f; hif = 0.0f; }
    half_t lo = (half_t)((w - hif) * 4096.0f);
    int n_tile = n >> 4, lr = n & 15;
    int k_chunk = k >> 5, kin = k & 31, quad = kin >> 3, j = kin & 7;
    size_t base = (size_t)(n_tile * kchunks + k_chunk) * 1024;
    size_t off  = base + (size_t)((quad << 4) + lr) * 8 + j;
    out[off]       = hi;
    out[off + 512] = lo;
}

__global__ __launch_bounds__(256)
void prep_w_kernel(const float* __restrict__ W1, const float* __restrict__ W2,
                   const float* __restrict__ W3,
                   half_t* __restrict__ ws1, half_t* __restrict__ ws2,
                   half_t* __restrict__ ws3) {
    int e = blockIdx.x * blockDim.x + threadIdx.x;   // 0..131071
    if (e < H1 * F_INPUT) {                          // 256 x 128, kchunks=4
        split_store_sw(W1[e], ws1, e / F_INPUT, e % F_INPUT, F_INPUT / 32);
    } else if (e < H1 * F_INPUT + H2 * H1) {         // 256 x 256, kchunks=8
        int i = e - H1 * F_INPUT;
        split_store_sw(W2[i], ws2, i / H1, i % H1, H1 / 32);
    } else {                                         // 128 x 256, kchunks=8
        int i = e - H1 * F_INPUT - H2 * H1;
        split_store_sw(W3[i], ws3, i / H2, i % H2, H2 / 32);
    }
}

// ---------------------------------------------------------------------------
// LDS geometry (unchanged from R7/R9): spk aliases As; 49 KB -> 2 blocks/CU.
// ---------------------------------------------------------------------------
#define CUR_STRIDE 260   // floats; cur tile [32][CUR_STRIDE] (also hist scratch)
#define AS_STRIDE  136   // halfs;  rates  [32][AS_STRIDE]
#define SPK_STRIDE 264   // halfs;  spikes [32][SPK_STRIDE]
#define SMEM_CUR   0                      // 32*260*4 = 33280 B
#define SMEM_AS    33280                  // As: 8704 B  } aliased: max = 16896
#define SMEM_SPK   33280                  // spk: 16896 B}
#define SMEM_TOTAL 50176                  // 49 KB; x2 blocks/CU = 98 KB < 160

// GEMM phase (unchanged from R9): C = sum A*(hi + 2^-12 lo) + bias, depth-1
// W prefetch, per-accumulator MFMA order fixed -> bit-identical across rounds.
template<int KCHUNKS, int NT, int ASTRIDE>
__device__ __forceinline__ void gemm_phase(const half_t* __restrict__ Wsw,
                                           const float*  __restrict__ bias,
                                           const half_t* __restrict__ Als,
                                           float* __restrict__ curT,
                                           int wave, int lane) {
    const int quad = lane >> 4, lr = lane & 15;
    float4v acc_h[2][NT], acc_l[2][NT];
#pragma unroll
    for (int mt = 0; mt < 2; ++mt)
#pragma unroll
        for (int nt = 0; nt < NT; ++nt) {
            acc_h[mt][nt] = (float4v){0.0f, 0.0f, 0.0f, 0.0f};
            acc_l[mt][nt] = (float4v){0.0f, 0.0f, 0.0f, 0.0f};
        }

    half8 wh[NT], wl[NT];
#pragma unroll
    for (int nt = 0; nt < NT; ++nt) {
        const half_t* p = Wsw + ((size_t)(wave * NT + nt) * KCHUNKS) * 1024 + lane * 8;
        wh[nt] = *(const half8*)(p);
        wl[nt] = *(const half8*)(p + 512);
    }

#pragma unroll
    for (int c = 0; c < KCHUNKS; ++c) {
        half8 a0 = *(const half8*)(Als + lr * ASTRIDE        + c * 32 + quad * 8);
        half8 a1 = *(const half8*)(Als + (16 + lr) * ASTRIDE + c * 32 + quad * 8);
        half8 nwh[NT], nwl[NT];
        if (c + 1 < KCHUNKS) {
#pragma unroll
            for (int nt = 0; nt < NT; ++nt) {
                const half_t* p =
                    Wsw + ((size_t)(wave * NT + nt) * KCHUNKS + c + 1) * 1024 + lane * 8;
                nwh[nt] = *(const half8*)(p);
                nwl[nt] = *(const half8*)(p + 512);
            }
        }
#pragma unroll
        for (int nt = 0; nt < NT; ++nt) {
            acc_h[0][nt] = __builtin_amdgcn_mfma_f32_16x16x32_f16(a0, wh[nt], acc_h[0][nt], 0, 0, 0);
            acc_h[1][nt] = __builtin_amdgcn_mfma_f32_16x16x32_f16(a1, wh[nt], acc_h[1][nt], 0, 0, 0);
            acc_l[0][nt] = __builtin_amdgcn_mfma_f32_16x16x32_f16(a0, wl[nt], acc_l[0][nt], 0, 0, 0);
            acc_l[1][nt] = __builtin_amdgcn_mfma_f32_16x16x32_f16(a1, wl[nt], acc_l[1][nt], 0, 0, 0);
        }
#pragma unroll
        for (int nt = 0; nt < NT; ++nt) { wh[nt] = nwh[nt]; wl[nt] = nwl[nt]; }
    }

    // epilogue -> curT (C/D layout: col=lane&15, row=quad*4+reg)
#pragma unroll
    for (int nt = 0; nt < NT; ++nt) {
        int col = wave * NT * 16 + nt * 16 + lr;
        float bj = bias[col];
#pragma unroll
        for (int mt = 0; mt < 2; ++mt) {
            int rbase = mt * 16 + quad * 4;
#pragma unroll
            for (int r = 0; r < 4; ++r) {
                float v = acc_h[mt][nt][r] + 2.44140625e-04f * acc_l[mt][nt][r];
                curT[(rbase + r) * CUR_STRIDE + col] = v + bj;
            }
        }
    }
}

// ---------------------------------------------------------------------------
// Mega kernel: one block = one batch b, 512 threads (8 waves).
// CHANGED vs R9: encode is SINGLE-PASS with fully-unrolled loads into
// registers. R9's rolled s-loops serialized one outstanding global load per
// iteration (~900 cyc HBM-cold each after the ws-poison flushes L2/L3):
// ~18-20 us of pure latency on every co-resident block simultaneously —
// invisible to occupancy/pipelining changes, which is exactly the R6-R9
// null-result signature. Math is value-identical (same gate/order/chain).
// ---------------------------------------------------------------------------
__global__ __launch_bounds__(512, 4)
void snn_mega_kernel(const float* __restrict__ x,
                     const half_t* __restrict__ ws1, const float* __restrict__ b1,
                     const half_t* __restrict__ ws2, const float* __restrict__ b2,
                     const half_t* __restrict__ ws3, const float* __restrict__ b3,
                     float* __restrict__ out) {
    __shared__ __align__(16) char smem[SMEM_TOTAL];
    float*  curT = (float*) (smem + SMEM_CUR);   // also hist/minmax scratch
    half_t* As   = (half_t*)(smem + SMEM_AS);    // aliases spk (As dead first)
    half_t* spk  = (half_t*)(smem + SMEM_SPK);

    const int tid  = threadIdx.x;
    const int b    = blockIdx.x;
    const int wave = tid >> 6;
    const int lane = tid & 63;

    // ================= phase 0: latency encode (threads 0..255) ===========
    const int f  = tid & 127;
    const int sh = (tid >> 7) & 1;               // s-half: 0 -> s 0..31, 1 -> 32..63
    const float* xp = x + (size_t)b * (S_SZ * F_INPUT) + (size_t)sh * 32 * F_INPUT + f;
    float* scratch = curT;

    float v[32];                                 // gated x, registers (no spill:
                                                 // kernel peak pressure is the
                                                 // ~110-VGPR GEMM phase, cap 128)
    if (tid < 256) {
        // burst all 32 loads (independent, all in flight), gate at ENC_THR
#pragma unroll
        for (int s = 0; s < 32; ++s) {
            float val = xp[(size_t)s * F_INPUT];
            v[s] = (val < 0.75f) ? 0.0f : val;
        }
        float mn = 1e30f, mx = -1e30f;
#pragma unroll
        for (int s = 0; s < 32; ++s) {
            mn = fminf(mn, v[s]);
            mx = fmaxf(mx, v[s]);
        }
        scratch[sh * 128 + f]       = mn;
        scratch[256 + sh * 128 + f] = mx;
    }
    __syncthreads();
    // exact: min(min half0, min half1) == min(all); same for max
    float fmn = fminf(scratch[f], scratch[128 + f]);
    float fmx = fmaxf(scratch[256 + f], scratch[384 + f]);
    __syncthreads();

    if (tid < 256) {
        float* hist = scratch;                   // hist[2][32][128] f32
#pragma unroll
        for (int t = 0; t < T_STEPS; ++t) hist[sh * 4096 + t * 128 + f] = 0.0f;
        // no barrier needed: each thread touches only its own (sh,*,f) cells
        const float denom = fmx - fmn + 1e-8f;
#pragma unroll
        for (int s = 0; s < 32; ++s) {
            float g = v[s];                      // reuse register value (identical
                                                 // to R9's reload of the same x)
            float xn = (g - fmn) / denom;
            float d  = fmaxf(xn, 0.0100001f);        // clip(xn, LAT_THR+EPS)
            float tt = logf(d / (d - 0.01f));        // log latency code
            tt = tt * 31.0f;
            tt = tt / 11.512935464920229f;           // float32(log((thr+eps)/eps))
            float tr = rintf(tt);                    // half-to-even == jnp.round
            tr = fminf(fmaxf(tr, 0.0f), 31.0f);
            hist[sh * 4096 + (int)tr * 128 + f] += 1.0f;
        }
    }
    __syncthreads();

    // merge halves -> rates (exact k/64) into As[t][f]; all 512 threads
#pragma unroll
    for (int i = 0; i < 8; ++i) {
        int idx = tid + i * 512;                 // 0..4095
        int t = idx >> 7, ff = idx & 127;
        float cnt = scratch[t * 128 + ff] + scratch[4096 + t * 128 + ff];
        As[t * AS_STRIDE + ff] = (half_t)(cnt * 0.015625f);
    }
    __syncthreads();

    // ================= layer 1: GEMM (K=128, N=256) + LIF =================
    gemm_phase<F_INPUT / 32, 2, AS_STRIDE>(ws1, b1, As, curT, wave, lane);
    __syncthreads();   // all As reads done; spk may now overwrite As region
    if (tid < 256) {
#pragma clang fp contract(off)
        const int h = tid;
        float mem = 0.0f;
#pragma unroll
        for (int t = 0; t < T_STEPS; ++t) {
            float c = curT[t * CUR_STRIDE + h];
            float reset = (mem - 1.0f > 0.0f) ? 1.0f : 0.0f;
            float p = 0.9f * mem;
            p = p + c;
            mem = p - reset;
            spk[t * SPK_STRIDE + h] = (half_t)((mem - 1.0f > 0.0f) ? 1.0f : 0.0f);
        }
    }
    __syncthreads();

    // ================= layer 2: GEMM (K=256, N=256) + LIF =================
    gemm_phase<H1 / 32, 2, SPK_STRIDE>(ws2, b2, spk, curT, wave, lane);
    __syncthreads();
    if (tid < 256) {
#pragma clang fp contract(off)
        const int h = tid;
        float mem = 0.0f;
#pragma unroll
        for (int t = 0; t < T_STEPS; ++t) {
            float c = curT[t * CUR_STRIDE + h];
            float reset = (mem - 1.0f > 0.0f) ? 1.0f : 0.0f;
            float p = 0.9f * mem;
            p = p + c;
            mem = p - reset;
            spk[t * SPK_STRIDE + h] = (half_t)((mem - 1.0f > 0.0f) ? 1.0f : 0.0f);
        }
    }
    __syncthreads();

    // ================= layer 3: GEMM (K=256, N=128) + LIF -> out ==========
    gemm_phase<H2 / 32, 1, SPK_STRIDE>(ws3, b3, spk, curT, wave, lane);
    __syncthreads();
    if (tid < H3) {
#pragma clang fp contract(off)
        const int h = tid;
        float mem = 0.0f;
#pragma unroll
        for (int t = 0; t < T_STEPS; ++t) {
            float c = curT[t * CUR_STRIDE + h];
            float reset = (mem - 1.0f > 0.0f) ? 1.0f : 0.0f;
            float p = 0.9f * mem;
            p = p + c;
            mem = p - reset;
            // reference output layout: [t*B + b][h], f32
            out[((size_t)t * B_SZ + b) * H3 + h] = (mem - 1.0f > 0.0f) ? 1.0f : 0.0f;
        }
    }
}

// ---------------------------------------------------------------------------
extern "C" void kernel_launch(void* const* d_in, const int* in_sizes, int n_in,
                              void* d_out, int out_size, void* d_ws, size_t ws_size,
                              hipStream_t stream) {
    const float* x  = (const float*)d_in[0];
    const float* W1 = (const float*)d_in[1];
    const float* b1 = (const float*)d_in[2];
    const float* W2 = (const float*)d_in[3];
    const float* b2 = (const float*)d_in[4];
    const float* W3 = (const float*)d_in[5];
    const float* b3 = (const float*)d_in[6];
    float* out = (float*)d_out;

    char* ws = (char*)d_ws;
    half_t* ws1 = (half_t*)ws;                          // 128 KB (swizzled hi/lo)
    half_t* ws2 = (half_t*)(ws + 128 * 1024);           // 256 KB
    half_t* ws3 = (half_t*)(ws + 384 * 1024);           // 128 KB

    // 0. split + swizzle weights (one dispatch, all layers)
    prep_w_kernel<<<(H1 * F_INPUT + H2 * H1 + H3 * H2) / 256, 256, 0, stream>>>(
        W1, W2, W3, ws1, ws2, ws3);

    // 1. whole network: one block per batch, 8 waves, spikes stay in LDS
    snn_mega_kernel<<<B_SZ, 512, 0, stream>>>(x, ws1, b1, ws2, b2, ws3, b3, out);
}